// Round 6
// baseline (821.974 us; speedup 1.0000x reference)
//
#include <hip/hip_runtime.h>

#define EMB   256
#define HID   128
#define RELD  64
#define NREL  10
#define TE    128
#define NB    512     // src-bucket count for the locality sort

typedef __attribute__((ext_vector_type(8)))  short bf16x8;
typedef __attribute__((ext_vector_type(16))) float f32x16;

__device__ __forceinline__ float bf16_to_f32(unsigned short u) {
    union { unsigned int i; float f; } v;
    v.i = ((unsigned int)u) << 16;
    return v.f;
}

__device__ __forceinline__ unsigned short f32_to_bf16(float x) {
    union { unsigned int i; float f; } v;
    v.f = x;
    unsigned int b = v.i;
    unsigned int rounded = b + 0x7fffu + ((b >> 16) & 1u);   // round-nearest-even
    return (unsigned short)(rounded >> 16);
}

template <bool F32>
__device__ __forceinline__ float ldx(const void* p, size_t i) {
    if (F32) return ((const float*)p)[i];
    return bf16_to_f32(((const unsigned short*)p)[i]);
}

// In-kernel parallel dtype detect (validated rounds 7-12: fp32 inputs -> true).
__device__ __forceinline__ bool detect_f32(const void* nodeEmb) {
    const float* f = (const float*)nodeEmb;
    float x = f[(threadIdx.x & 63) * 997];
    bool sane = isfinite(x) && fabsf(x) < 1.0e6f;
    unsigned long long m = __ballot(sane);
    return __popcll(m) >= 48;
}

// Register-free async global->LDS (16B per lane). LDS dest must be the
// wave-uniform base; HW adds lane*16.
__device__ __forceinline__ void gload16(const void* g, void* l) {
    __builtin_amdgcn_global_load_lds(
        (const __attribute__((address_space(1))) unsigned int*)g,
        (__attribute__((address_space(3))) unsigned int*)l, 16, 0, 0);
}

// ---------------------------------------------------------------------------
// Merged prep kernel:
//   blocks [0, convBlocks)    : fp32 node table -> bf16 copy
//   blocks [convBlocks, +448) : weights -> bf16 in MFMA-FRAGMENT ORDER: per
//                               K-chunk (32 k), 512 16-B units, unit g holds
//                               W[kc*32 + (g>>7)*8 .. +7][g&127].
//   block  convBlocks+448     : per-relation Q table (10x128 fp32)
//                               + zero the sort hist/cursor arrays
// ---------------------------------------------------------------------------
template <bool F32>
__device__ void prep_body(int vb, const void* W_edge, const void* W_k,
                          const void* W_v, const void* W_o1, const void* rel_emb,
                          const void* W_q, const void* b_q,
                          unsigned short* WTe, unsigned short* WTk,
                          unsigned short* WTv, unsigned short* WTo1, float* Qtab,
                          int* hist)
{
    if (vb < 448) {
        int idx = vb * 256 + threadIdx.x;             // 0 .. 114687
        if (idx < 65536) {                            // W_edge: 16 chunks x 4096
            int kc = idx >> 12, e = idx & 4095;
            int g = e >> 3, j = e & 7;
            int col = g & 127, kg = g >> 7;
            int k = kc * 32 + kg * 8 + j;
            WTe[idx] = f32_to_bf16(ldx<F32>(W_edge, (size_t)k * HID + col));
        } else if (idx < 65536 + 16384) {             // W_k: 4 chunks x 4096
            int i = idx - 65536;
            int kc = i >> 12, e = i & 4095;
            int g = e >> 3, j = e & 7;
            int col = g & 127, kg = (g >> 7) & 3;
            int k = kc * 32 + kg * 8 + j;
            WTk[i] = f32_to_bf16(ldx<F32>(W_k, (size_t)k * HID + col));
        } else if (idx < 65536 + 2 * 16384) {
            int i = idx - 65536 - 16384;
            int kc = i >> 12, e = i & 4095;
            int g = e >> 3, j = e & 7;
            int col = g & 127, kg = (g >> 7) & 3;
            int k = kc * 32 + kg * 8 + j;
            WTv[i] = f32_to_bf16(ldx<F32>(W_v, (size_t)k * HID + col));
        } else {
            int i = idx - 65536 - 2 * 16384;
            int kc = i >> 12, e = i & 4095;
            int g = e >> 3, j = e & 7;
            int col = g & 127, kg = (g >> 7) & 3;
            int k = kc * 32 + kg * 8 + j;
            WTo1[i] = f32_to_bf16(ldx<F32>(W_o1, (size_t)k * HID + col));
        }
    } else {
        const int t = threadIdx.x;
        // zero sort arrays (hist[NB] + cursor[NB], contiguous 2*NB ints)
        for (int i = t; i < 2 * NB; i += 256) hist[i] = 0;
        const int c = t & (HID - 1);
        const int h = t >> 7;
        for (int r = h; r < NREL; r += 2) {
            float acc = 0.f;
            for (int d = 0; d < RELD; ++d)
                acc += ldx<F32>(rel_emb, r * RELD + d) * ldx<F32>(W_q, (size_t)d * HID + c);
            Qtab[r * HID + c] = acc + ldx<F32>(b_q, c);
        }
    }
}

__global__ void prep_kernel(const void* nodeEmb,
                            const void* W_edge, const void* W_k, const void* W_v,
                            const void* W_o1, const void* rel_emb, const void* W_q,
                            const void* b_q,
                            unsigned short* WTe, unsigned short* WTk,
                            unsigned short* WTv, unsigned short* WTo1, float* Qtab,
                            unsigned short* nodeBf16, int convBlocks,
                            unsigned long long nodeElems, int* hist)
{
    bool f32 = detect_f32(nodeEmb);
    int b = blockIdx.x;
    if (b < convBlocks) {
        if (!f32) return;                             // bf16 input: no conversion
        unsigned long long i = (unsigned long long)b * 2048ull + threadIdx.x * 8;
        if (i + 8 <= nodeElems) {
            const float* src = (const float*)nodeEmb + i;
            float4 f0 = *(const float4*)src;
            float4 f1 = *(const float4*)(src + 4);
            union { unsigned short us[8]; uint4 v; } pk;
            pk.us[0] = f32_to_bf16(f0.x); pk.us[1] = f32_to_bf16(f0.y);
            pk.us[2] = f32_to_bf16(f0.z); pk.us[3] = f32_to_bf16(f0.w);
            pk.us[4] = f32_to_bf16(f1.x); pk.us[5] = f32_to_bf16(f1.y);
            pk.us[6] = f32_to_bf16(f1.z); pk.us[7] = f32_to_bf16(f1.w);
            *(uint4*)(nodeBf16 + i) = pk.v;
        }
        return;
    }
    b -= convBlocks;
    if (f32) prep_body<true >(b, W_edge, W_k, W_v, W_o1, rel_emb, W_q, b_q,
                              WTe, WTk, WTv, WTo1, Qtab, hist);
    else     prep_body<false>(b, W_edge, W_k, W_v, W_o1, rel_emb, W_q, b_q,
                              WTe, WTk, WTv, WTo1, Qtab, hist);
}

// --------------------- locality sort (counting sort by src>>shift) ----------
__global__ void sort_hist_kernel(const int* edgeIdx, int E, int shift, int* hist) {
    int e = blockIdx.x * 256 + threadIdx.x;
    if (e < E) {
        int b = edgeIdx[e] >> shift;
        if (b < 0) b = 0;
        if (b >= NB) b = NB - 1;
        atomicAdd(&hist[b], 1);
    }
}

__global__ void sort_scan_kernel(const int* hist, int* curs) {
    __shared__ int tmp[NB];
    int t = threadIdx.x;
    int v0 = hist[t];
    tmp[t] = v0;
    __syncthreads();
    for (int d = 1; d < NB; d <<= 1) {
        int v = (t >= d) ? tmp[t - d] : 0;
        __syncthreads();
        tmp[t] += v;
        __syncthreads();
    }
    curs[t] = tmp[t] - v0;        // exclusive prefix
}

__global__ void sort_scatter_kernel(const int* edgeIdx, int E, int shift,
                                    int* curs, int* perm) {
    int e = blockIdx.x * 256 + threadIdx.x;
    if (e < E) {
        int b = edgeIdx[e] >> shift;
        if (b < 0) b = 0;
        if (b >= NB) b = NB - 1;
        int pos = atomicAdd(&curs[b], 1);
        perm[pos] = e;
    }
}

// ---------------------------------------------------------------------------
// Shared memory, ~80 KB -> 2 blocks/CU (16 waves). All MFMA-side tiles are in
// FRAGMENT ORDER (unit u = 16B):
//   SA chunk:  u = s*256 + h5*128 + row       (A, 128 rows x 32 k)
//   SB chunk:  u = (s*2+h5)*128 + col         (B, 32 k x 128 cols, = WT layout)
//   sHid:      u = kg*128 + row, kg = k>>3    (128 rows x 128 k)
// ---------------------------------------------------------------------------
struct __align__(16) Smem {
    unsigned short sHid[16 * 128 * 8];   // 32768 B
    unsigned short SA[2][4096];          // 16384 B: double-buffered A chunk
    unsigned short SB[2][4096];          // 16384 B: double-buffered B chunk
    float sQf[NREL * HID];               // 5120 B
    float sBias[5 * HID];                // 2560 B: b_edge|b_k|b_v|b_o1|W_o2
    float sSc[TE][4];                    // 2048 B
    float sAttn[TE][4];                  // 2048 B
    float sPart[TE][2];                  // 1024 B
    int   sSrc[TE], sTgt[TE], sRel[TE];  // 1536 B
    int   sEid[TE];                      // 512 B: original edge id (output idx)
};

// sHid element address (row, k) -> short index
__device__ __forceinline__ int shid_idx(int row, int k) {
    return (((k >> 3) * 128 + row) << 3) + (k & 7);
}

// ---------------------------------------------------------------------------
// Fused pipeline, 32x32x16 MFMA. Block = 128 edges, 512 threads = 8 waves.
// Edges are processed in src-bucket-sorted order (perm) with an XCD-chunked
// bijective block swizzle: XCD x (= blockIdx%8, HW round-robin) walks a
// contiguous range of src buckets, so its private L2 streams a ~6.4 MB slice
// of the node table instead of random-missing the whole 51 MB. Output scatter
// uses the ORIGINAL edge id, so processing order is correctness-neutral.
// ---------------------------------------------------------------------------
template <bool F32, bool GBF16>
__device__ void fused_body(
    Smem& sm,
    const void* gsrc, const int* edgeIdx, const int* relType,
    const unsigned short* WTe, const unsigned short* WTk,
    const unsigned short* WTv, const unsigned short* WTo1,
    const void* b_edge, const void* b_k, const void* b_v,
    const void* b_o1, const void* W_o2, const void* b_o2,
    const float* Qtab, const int* perm, int usePerm, void* outp, int E)
{
    const int t   = threadIdx.x;
    const int l   = t & 63;
    const int w   = t >> 6;          // 0..7
    const int c   = l & 31;
    const int h5  = l >> 5;
    const int rt  = w >> 1;          // 0..3  row tile
    const int cg2 = w & 1;           // 0..1  col tile

    // XCD-chunked bijective block remap (m204 formula), only with perm.
    int wi;
    {
        int G = (int)gridDim.x;
        int b = (int)blockIdx.x;
        if (usePerm) {
            int q = G >> 3, r = G & 7;
            int x = b & 7, o = b >> 3;
            wi = (x < r) ? x * (q + 1) + o : r * (q + 1) + (x - r) * q + o;
        } else {
            wi = b;
        }
    }
    const int bs   = wi * TE;
    const int aRow = 32 * rt + c;

    // ---- preamble ----
    if (t < TE) {
        int ge = bs + t;
        if (ge >= E) ge = E - 1;
        if (ge < 0)  ge = 0;
        int e = usePerm ? perm[ge] : ge;
        if (e < 0)  e = 0;
        if (e >= E) e = E - 1;
        sm.sEid[t] = e;
        sm.sSrc[t] = edgeIdx[e];
        sm.sTgt[t] = edgeIdx[E + e];
        int r = relType[e];
        if (r < 0) r = 0;
        if (r >= NREL) r = NREL - 1;
        sm.sRel[t] = r;
    }
    for (int i = t; i < 5 * HID; i += 512) {
        int which = i >> 7, j = i & (HID - 1);
        float v = (which == 0) ? ldx<F32>(b_edge, j)
                : (which == 1) ? ldx<F32>(b_k, j)
                : (which == 2) ? ldx<F32>(b_v, j)
                : (which == 3) ? ldx<F32>(b_o1, j)
                               : ldx<F32>(W_o2, j);
        sm.sBias[i] = v;
    }
    for (int i = t; i < NREL * HID; i += 512)
        sm.sQf[i] = Qtab[i];
    __syncthreads();

    // staging role of this thread: unit t = (s, h5, row)
    const int    stS   = t >> 8;          // 0..1
    const int    stH5  = (t >> 7) & 1;
    const int    stRow = t & 127;
    const size_t rowOffS = (size_t)sm.sSrc[stRow] * EMB;
    const size_t rowOffT = (size_t)sm.sTgt[stRow] * EMB;
    const int    colSub  = stS * 16 + stH5 * 8;     // element offset in 32-chunk
    char* const  ldsWaveA0 = (char*)sm.SA[0] + w * 1024;
    char* const  ldsWaveA1 = (char*)sm.SA[1] + w * 1024;
    char* const  ldsWaveB0 = (char*)sm.SB[0] + w * 1024;
    char* const  ldsWaveB1 = (char*)sm.SB[1] + w * 1024;

    #define STAGE_A(kc, buf)                                                     \
    {                                                                            \
        size_t eoff = (((kc) < 8) ? rowOffS : rowOffT)                           \
                      + (size_t)(((kc) & 7) * 32 + colSub);                      \
        if (GBF16) {                                                             \
            gload16((const unsigned short*)gsrc + eoff,                          \
                    (buf) ? ldsWaveA1 : ldsWaveA0);                              \
        } else {                                                                 \
            const float* p_ = (const float*)gsrc + eoff;                         \
            float4 f0_ = *(const float4*)p_;                                     \
            float4 f1_ = *(const float4*)(p_ + 4);                               \
            union { unsigned short us[8]; uint4 v; } pk_;                        \
            pk_.us[0] = f32_to_bf16(f0_.x); pk_.us[1] = f32_to_bf16(f0_.y);      \
            pk_.us[2] = f32_to_bf16(f0_.z); pk_.us[3] = f32_to_bf16(f0_.w);      \
            pk_.us[4] = f32_to_bf16(f1_.x); pk_.us[5] = f32_to_bf16(f1_.y);      \
            pk_.us[6] = f32_to_bf16(f1_.z); pk_.us[7] = f32_to_bf16(f1_.w);      \
            *(uint4*)((char*)sm.SA[(buf)] + t * 16) = pk_.v;                     \
        }                                                                        \
    }

    #define STAGE_B(WT, kc, buf)                                                 \
        gload16((WT) + (kc) * 4096 + t * 8, (buf) ? ldsWaveB1 : ldsWaveB0);

    // MFMA on one staged chunk: A from SA[buf], B from SB[buf]
    #define MFMA_SA(buf, accv)                                                   \
    {                                                                            \
        const char* sa_ = (const char*)sm.SA[(buf)];                             \
        const char* sb_ = (const char*)sm.SB[(buf)];                             \
        _Pragma("unroll")                                                        \
        for (int s_ = 0; s_ < 2; ++s_) {                                         \
            bf16x8 a_ = *(const bf16x8*)(sa_ + ((s_ * 256 + h5 * 128 + aRow) << 4)); \
            _Pragma("unroll")                                                    \
            for (int ct_ = 0; ct_ < 2; ++ct_) {                                  \
                bf16x8 b_ = *(const bf16x8*)                                     \
                    (sb_ + ((s_ * 256 + h5 * 128 + 64 * cg2 + 32 * ct_ + c) << 4)); \
                accv[ct_] = __builtin_amdgcn_mfma_f32_32x32x16_bf16(             \
                                a_, b_, accv[ct_], 0, 0, 0);                     \
            }                                                                    \
        }                                                                        \
    }

    // MFMA with A from sHid (fragment order), B from SB[buf]
    #define MFMA_H(kc, buf, accv)                                                \
    {                                                                            \
        const char* sb_ = (const char*)sm.SB[(buf)];                             \
        _Pragma("unroll")                                                        \
        for (int s_ = 0; s_ < 2; ++s_) {                                         \
            bf16x8 a_ = *(const bf16x8*)((const char*)sm.sHid +                  \
                         ((((kc) * 4 + s_ * 2 + h5) * 128 + aRow) << 4));        \
            _Pragma("unroll")                                                    \
            for (int ct_ = 0; ct_ < 2; ++ct_) {                                  \
                bf16x8 b_ = *(const bf16x8*)                                     \
                    (sb_ + ((s_ * 256 + h5 * 128 + 64 * cg2 + 32 * ct_ + c) << 4)); \
                accv[ct_] = __builtin_amdgcn_mfma_f32_32x32x16_bf16(             \
                                a_, b_, accv[ct_], 0, 0, 0);                     \
            }                                                                    \
        }                                                                        \
    }

    // ---- GEMM1: hid = relu([src|tgt] @ W_edge + b_edge), K=512, 16 chunks ----
    f32x16 acc[2];
    acc[0] = (f32x16)(0.0f); acc[1] = (f32x16)(0.0f);
    STAGE_A(0, 0); STAGE_B(WTe, 0, 0);
    __syncthreads();                     // chunk 0 staged (vmcnt drained)
    #pragma unroll
    for (int kc = 0; kc < 16; ++kc) {
        int buf = kc & 1;
        if (kc < 15) { STAGE_A(kc + 1, buf ^ 1); STAGE_B(WTe, kc + 1, buf ^ 1); }
        MFMA_SA(buf, acc);
        __syncthreads();                 // next chunk staged; buf consumed
    }
    {   // epilogue: + b_edge, relu -> sHid (bf16, fragment order)
        #pragma unroll
        for (int ct = 0; ct < 2; ++ct) {
            int col = 64 * cg2 + 32 * ct + c;
            float bb = sm.sBias[col];
            #pragma unroll
            for (int r = 0; r < 16; ++r) {
                int erow = 32 * rt + (r & 3) + 8 * (r >> 2) + 4 * h5;
                sm.sHid[shid_idx(erow, col)] = f32_to_bf16(fmaxf(acc[ct][r] + bb, 0.f));
            }
        }
    }

    // ---- K GEMM: K=128, 4 chunks, A resident in sHid ----
    f32x16 kacc[2];
    kacc[0] = (f32x16)(0.0f); kacc[1] = (f32x16)(0.0f);
    STAGE_B(WTk, 0, 0);
    __syncthreads();                     // sHid visible + chunk 0 staged
    #pragma unroll
    for (int kc = 0; kc < 4; ++kc) {
        int buf = kc & 1;
        if (kc < 3) STAGE_B(WTk, kc + 1, buf ^ 1);
        MFMA_H(kc, buf, kacc);
        __syncthreads();
    }

    // ---- scores[e][h] = sum_col Q[rel][col]*(K+bk)[e][col] / sqrt(32) ----
    {
        float ps[2][16];
        #pragma unroll
        for (int ct = 0; ct < 2; ++ct) {
            int col = 64 * cg2 + 32 * ct + c;
            float bk = sm.sBias[HID + col];
            #pragma unroll
            for (int r = 0; r < 16; ++r) {
                int erow = 32 * rt + (r & 3) + 8 * (r >> 2) + 4 * h5;
                ps[ct][r] = (kacc[ct][r] + bk) * sm.sQf[sm.sRel[erow] * HID + col];
            }
        }
        #pragma unroll
        for (int m = 1; m < 32; m <<= 1)
            #pragma unroll
            for (int ct = 0; ct < 2; ++ct)
                #pragma unroll
                for (int r = 0; r < 16; ++r)
                    ps[ct][r] += __shfl_xor(ps[ct][r], m, 64);
        if (c == 0) {
            const float inv = 0.17677669529663687f;   // 1/sqrt(32)
            #pragma unroll
            for (int ct = 0; ct < 2; ++ct) {
                int head = 2 * cg2 + ct;
                #pragma unroll
                for (int r = 0; r < 16; ++r) {
                    int erow = 32 * rt + (r & 3) + 8 * (r >> 2) + 4 * h5;
                    sm.sSc[erow][head] = ps[ct][r] * inv;
                }
            }
        }
    }
    __syncthreads();
    if (t < TE) {   // softmax over 4 heads
        float s0 = sm.sSc[t][0], s1 = sm.sSc[t][1];
        float s2 = sm.sSc[t][2], s3 = sm.sSc[t][3];
        float m = fmaxf(fmaxf(s0, s1), fmaxf(s2, s3));
        float e0 = expf(s0 - m), e1 = expf(s1 - m);
        float e2 = expf(s2 - m), e3 = expf(s3 - m);
        float den = e0 + e1 + e2 + e3;
        sm.sAttn[t][0] = e0 / den; sm.sAttn[t][1] = e1 / den;
        sm.sAttn[t][2] = e2 / den; sm.sAttn[t][3] = e3 / den;
    }
    __syncthreads();

    // ---- V GEMM ----
    f32x16 vacc[2];
    vacc[0] = (f32x16)(0.0f); vacc[1] = (f32x16)(0.0f);
    STAGE_B(WTv, 0, 0);
    __syncthreads();
    #pragma unroll
    for (int kc = 0; kc < 4; ++kc) {
        int buf = kc & 1;
        if (kc < 3) STAGE_B(WTv, kc + 1, buf ^ 1);
        MFMA_H(kc, buf, vacc);
        __syncthreads();                 // final iter: fences all sHid A-reads
    }

    // ---- attend + residual (in-place on sHid; element-owner = this lane) ----
    {
        #pragma unroll
        for (int ct = 0; ct < 2; ++ct) {
            int col  = 64 * cg2 + 32 * ct + c;
            int head = 2 * cg2 + ct;
            float bv = sm.sBias[2 * HID + col];
            #pragma unroll
            for (int r = 0; r < 16; ++r) {
                int erow = 32 * rt + (r & 3) + 8 * (r >> 2) + 4 * h5;
                float at = sm.sAttn[erow][head];
                int   si = shid_idx(erow, col);
                float hv = bf16_to_f32(sm.sHid[si]);
                sm.sHid[si] = f32_to_bf16(at * (vacc[ct][r] + bv) + hv);
            }
        }
    }
    __syncthreads();                     // sHid updated for all waves

    // ---- GEMM3 + final dot with W_o2 ----
    f32x16 oacc[2];
    oacc[0] = (f32x16)(0.0f); oacc[1] = (f32x16)(0.0f);
    STAGE_B(WTo1, 0, 0);
    __syncthreads();
    #pragma unroll
    for (int kc = 0; kc < 4; ++kc) {
        int buf = kc & 1;
        if (kc < 3) STAGE_B(WTo1, kc + 1, buf ^ 1);
        MFMA_H(kc, buf, oacc);
        __syncthreads();
    }
    {
        float pr[16];
        #pragma unroll
        for (int r = 0; r < 16; ++r) pr[r] = 0.f;
        #pragma unroll
        for (int ct = 0; ct < 2; ++ct) {
            int col = 64 * cg2 + 32 * ct + c;
            float bo = sm.sBias[3 * HID + col];
            float wo = sm.sBias[4 * HID + col];
            #pragma unroll
            for (int r = 0; r < 16; ++r)
                pr[r] += fmaxf(oacc[ct][r] + bo, 0.f) * wo;
        }
        #pragma unroll
        for (int m = 1; m < 32; m <<= 1)
            #pragma unroll
            for (int r = 0; r < 16; ++r)
                pr[r] += __shfl_xor(pr[r], m, 64);
        if (c == 0) {
            #pragma unroll
            for (int r = 0; r < 16; ++r) {
                int erow = 32 * rt + (r & 3) + 8 * (r >> 2) + 4 * h5;
                sm.sPart[erow][cg2] = pr[r];
            }
        }
    }
    __syncthreads();
    if (t < TE) {
        int ge = bs + t;
        if (ge < E) {
            float val = sm.sPart[t][0] + sm.sPart[t][1] + ldx<F32>(b_o2, 0);
            int oe = sm.sEid[t];      // scatter to ORIGINAL edge position
            // F32 path writes fp32 (round-10 lesson: output buffer is fp32).
            if (F32) ((float*)outp)[oe] = val;
            else     ((unsigned short*)outp)[oe] = f32_to_bf16(val);
        }
    }

    #undef STAGE_A
    #undef STAGE_B
    #undef MFMA_SA
    #undef MFMA_H
}

__global__ __launch_bounds__(512, 4) void RelationAttentionMLPHead_10539849744626_kernel(
    const void* nodeEmb, const unsigned short* nodeBf16, int useConv,
    const int* edgeIdx, const int* relType,
    const unsigned short* WTe, const unsigned short* WTk,
    const unsigned short* WTv, const unsigned short* WTo1,
    const void* b_edge, const void* b_k, const void* b_v,
    const void* b_o1, const void* W_o2, const void* b_o2,
    const float* Qtab, const int* perm, int usePerm, void* outp, int E)
{
    __shared__ Smem sm;     // single allocation shared by all instantiations
    if (detect_f32(nodeEmb)) {
        if (useConv)
            fused_body<true, true >(sm, nodeBf16, edgeIdx, relType, WTe, WTk, WTv, WTo1,
                                    b_edge, b_k, b_v, b_o1, W_o2, b_o2, Qtab,
                                    perm, usePerm, outp, E);
        else
            fused_body<true, false>(sm, nodeEmb, edgeIdx, relType, WTe, WTk, WTv, WTo1,
                                    b_edge, b_k, b_v, b_o1, W_o2, b_o2, Qtab,
                                    perm, usePerm, outp, E);
    } else {
        // input already bf16: gather straight from the input table
        fused_body<false, true>(sm, nodeEmb, edgeIdx, relType, WTe, WTk, WTv, WTo1,
                                b_edge, b_k, b_v, b_o1, W_o2, b_o2, Qtab,
                                perm, usePerm, outp, E);
    }
}

extern "C" void kernel_launch(void* const* d_in, const int* in_sizes, int n_in,
                              void* d_out, int out_size, void* d_ws, size_t ws_size,
                              hipStream_t stream) {
    (void)n_in;

    const void* nodeEmb = d_in[0];
    const int*  edgeIdx = (const int*)d_in[1];
    const int*  relType = (const int*)d_in[2];
    const void* rel_emb = d_in[3];
    const void* W_edge  = d_in[4];
    const void* b_edge  = d_in[5];
    const void* W_q     = d_in[6];
    const void* b_q     = d_in[7];
    const void* W_k     = d_in[8];
    const void* b_k     = d_in[9];
    const void* W_v     = d_in[10];
    const void* b_v     = d_in[11];
    const void* W_o1    = d_in[12];
    const void* b_o1    = d_in[13];
    const void* W_o2    = d_in[14];
    const void* b_o2    = d_in[15];

    int E = out_size;
    if (E <= 0) E = in_sizes ? in_sizes[2] : 0;
    if (E <= 0) E = 500000;

    unsigned long long nodeElems =
        (in_sizes && in_sizes[0] > 0) ? (unsigned long long)in_sizes[0] : 25600000ull;
    unsigned long long nodeRows = nodeElems / EMB;
    if (nodeRows < 1) nodeRows = 1;

    // bucket shift: (nodeRows-1)>>shift < NB
    int shift = 0;
    while (((nodeRows - 1ull) >> shift) >= (unsigned long long)NB) ++shift;

    // d_ws layout (recomputed every launch; graph-safe)
    char* ws = (char*)d_ws;
    float*          Qtab = (float*)ws;                        // 5120 B (8192 rsvd)
    unsigned short* WTe  = (unsigned short*)(ws + 8192);      // 131072 B
    unsigned short* WTk  = (unsigned short*)(ws + 139264);    // 32768 B
    unsigned short* WTv  = (unsigned short*)(ws + 172032);    // 32768 B
    unsigned short* WTo1 = (unsigned short*)(ws + 204800);    // 32768 B
    int*            hist = (int*)(ws + 237568);               // NB*4   = 2048 B
    int*            curs = (int*)(ws + 239616);               // NB*4   = 2048 B
    int*            perm = (int*)(ws + 241664);               // E*4 B
    unsigned long long permBytes = ((unsigned long long)E * 4ull + 255ull) & ~255ull;
    unsigned short* nodeBf16 = (unsigned short*)(ws + 241664 + permBytes);

    size_t need = 241664ull + permBytes + nodeElems * 2ull;
    int useAll = (ws_size >= need) ? 1 : 0;       // conv + sort together
    int convBlocks = useAll ? (int)((nodeElems + 2047ull) / 2048ull) : 0;

    prep_kernel<<<convBlocks + 449, 256, 0, stream>>>(
        nodeEmb, W_edge, W_k, W_v, W_o1, rel_emb, W_q, b_q,
        WTe, WTk, WTv, WTo1, Qtab, nodeBf16, convBlocks, nodeElems, hist);

    if (useAll) {
        int sgrid = (E + 255) / 256;
        sort_hist_kernel<<<sgrid, 256, 0, stream>>>(edgeIdx, E, shift, hist);
        sort_scan_kernel<<<1, NB, 0, stream>>>(hist, curs);
        sort_scatter_kernel<<<sgrid, 256, 0, stream>>>(edgeIdx, E, shift, curs, perm);
    }

    int grid = (E + TE - 1) / TE;
    if (grid < 1) grid = 1;

    RelationAttentionMLPHead_10539849744626_kernel<<<grid, 512, 0, stream>>>(
        nodeEmb, nodeBf16, useAll, edgeIdx, relType, WTe, WTk, WTv, WTo1,
        b_edge, b_k, b_v, b_o1, W_o2, b_o2, Qtab, perm, useAll, d_out, E);
}

// Round 7
// 555.167 us; speedup vs baseline: 1.4806x; 1.4806x over previous
//
#include <hip/hip_runtime.h>

#define EMB   256
#define HID   128
#define RELD  64
#define NREL  10
#define TE    128

typedef __attribute__((ext_vector_type(8)))  short bf16x8;
typedef __attribute__((ext_vector_type(16))) float f32x16;

__device__ __forceinline__ float bf16_to_f32(unsigned short u) {
    union { unsigned int i; float f; } v;
    v.i = ((unsigned int)u) << 16;
    return v.f;
}

__device__ __forceinline__ unsigned short f32_to_bf16(float x) {
    union { unsigned int i; float f; } v;
    v.f = x;
    unsigned int b = v.i;
    unsigned int rounded = b + 0x7fffu + ((b >> 16) & 1u);   // round-nearest-even
    return (unsigned short)(rounded >> 16);
}

template <bool F32>
__device__ __forceinline__ float ldx(const void* p, size_t i) {
    if (F32) return ((const float*)p)[i];
    return bf16_to_f32(((const unsigned short*)p)[i]);
}

// In-kernel parallel dtype detect (validated rounds 7-12: fp32 inputs -> true).
__device__ __forceinline__ bool detect_f32(const void* nodeEmb) {
    const float* f = (const float*)nodeEmb;
    float x = f[(threadIdx.x & 63) * 997];
    bool sane = isfinite(x) && fabsf(x) < 1.0e6f;
    unsigned long long m = __ballot(sane);
    return __popcll(m) >= 48;
}

// Phase barrier that drains ONLY LDS ops (lgkmcnt). No vmcnt(0): in-flight
// global->register prefetches for the next phase survive the barrier.
// All cross-wave data exchange in this kernel goes through LDS, so vmcnt
// never needs draining at a barrier (global loads land in private VGPRs).
__device__ __forceinline__ void barrier_lgkm() {
    asm volatile("s_waitcnt lgkmcnt(0)" ::: "memory");
    __builtin_amdgcn_s_barrier();
    __builtin_amdgcn_sched_barrier(0);   // rule-18 safety: pin ordering
}

// ---------------------------------------------------------------------------
// Merged prep kernel (R2 version, sort removed):
//   blocks [0, convBlocks)    : fp32 node table -> bf16 copy
//   blocks [convBlocks, +448) : weights -> bf16 in MFMA-FRAGMENT ORDER: per
//                               K-chunk (32 k), 512 16-B units, unit g holds
//                               W[kc*32 + (g>>7)*8 .. +7][g&127].
//   block  convBlocks+448     : per-relation Q table (10x128 fp32)
// ---------------------------------------------------------------------------
template <bool F32>
__device__ void prep_body(int vb, const void* W_edge, const void* W_k,
                          const void* W_v, const void* W_o1, const void* rel_emb,
                          const void* W_q, const void* b_q,
                          unsigned short* WTe, unsigned short* WTk,
                          unsigned short* WTv, unsigned short* WTo1, float* Qtab)
{
    if (vb < 448) {
        int idx = vb * 256 + threadIdx.x;             // 0 .. 114687
        if (idx < 65536) {                            // W_edge: 16 chunks x 4096
            int kc = idx >> 12, e = idx & 4095;
            int g = e >> 3, j = e & 7;
            int col = g & 127, kg = g >> 7;
            int k = kc * 32 + kg * 8 + j;
            WTe[idx] = f32_to_bf16(ldx<F32>(W_edge, (size_t)k * HID + col));
        } else if (idx < 65536 + 16384) {             // W_k: 4 chunks x 4096
            int i = idx - 65536;
            int kc = i >> 12, e = i & 4095;
            int g = e >> 3, j = e & 7;
            int col = g & 127, kg = (g >> 7) & 3;
            int k = kc * 32 + kg * 8 + j;
            WTk[i] = f32_to_bf16(ldx<F32>(W_k, (size_t)k * HID + col));
        } else if (idx < 65536 + 2 * 16384) {
            int i = idx - 65536 - 16384;
            int kc = i >> 12, e = i & 4095;
            int g = e >> 3, j = e & 7;
            int col = g & 127, kg = (g >> 7) & 3;
            int k = kc * 32 + kg * 8 + j;
            WTv[i] = f32_to_bf16(ldx<F32>(W_v, (size_t)k * HID + col));
        } else {
            int i = idx - 65536 - 2 * 16384;
            int kc = i >> 12, e = i & 4095;
            int g = e >> 3, j = e & 7;
            int col = g & 127, kg = (g >> 7) & 3;
            int k = kc * 32 + kg * 8 + j;
            WTo1[i] = f32_to_bf16(ldx<F32>(W_o1, (size_t)k * HID + col));
        }
    } else {
        const int t = threadIdx.x;
        const int c = t & (HID - 1);
        const int h = t >> 7;
        for (int r = h; r < NREL; r += 2) {
            float acc = 0.f;
            for (int d = 0; d < RELD; ++d)
                acc += ldx<F32>(rel_emb, r * RELD + d) * ldx<F32>(W_q, (size_t)d * HID + c);
            Qtab[r * HID + c] = acc + ldx<F32>(b_q, c);
        }
    }
}

__global__ void prep_kernel(const void* nodeEmb,
                            const void* W_edge, const void* W_k, const void* W_v,
                            const void* W_o1, const void* rel_emb, const void* W_q,
                            const void* b_q,
                            unsigned short* WTe, unsigned short* WTk,
                            unsigned short* WTv, unsigned short* WTo1, float* Qtab,
                            unsigned short* nodeBf16, int convBlocks,
                            unsigned long long nodeElems)
{
    bool f32 = detect_f32(nodeEmb);
    int b = blockIdx.x;
    if (b < convBlocks) {
        if (!f32) return;                             // bf16 input: no conversion
        unsigned long long i = (unsigned long long)b * 2048ull + threadIdx.x * 8;
        if (i + 8 <= nodeElems) {
            const float* src = (const float*)nodeEmb + i;
            float4 f0 = *(const float4*)src;
            float4 f1 = *(const float4*)(src + 4);
            union { unsigned short us[8]; uint4 v; } pk;
            pk.us[0] = f32_to_bf16(f0.x); pk.us[1] = f32_to_bf16(f0.y);
            pk.us[2] = f32_to_bf16(f0.z); pk.us[3] = f32_to_bf16(f0.w);
            pk.us[4] = f32_to_bf16(f1.x); pk.us[5] = f32_to_bf16(f1.y);
            pk.us[6] = f32_to_bf16(f1.z); pk.us[7] = f32_to_bf16(f1.w);
            *(uint4*)(nodeBf16 + i) = pk.v;
        }
        return;
    }
    b -= convBlocks;
    if (f32) prep_body<true >(b, W_edge, W_k, W_v, W_o1, rel_emb, W_q, b_q,
                              WTe, WTk, WTv, WTo1, Qtab);
    else     prep_body<false>(b, W_edge, W_k, W_v, W_o1, rel_emb, W_q, b_q,
                              WTe, WTk, WTv, WTo1, Qtab);
}

// ---------------------------------------------------------------------------
// Shared memory, 47104 B (was 80 KB): all GEMM-operand staging buffers GONE.
// Only true cross-wave exchanges remain in LDS. sHid kept in fragment order:
// unit u(16B) = kg*128 + row, kg = k>>3.
// ---------------------------------------------------------------------------
struct __align__(16) Smem {
    unsigned short sHid[16 * 128 * 8];   // 32768 B
    float sQf[NREL * HID];               // 5120 B
    float sBias[5 * HID];                // 2560 B: b_edge|b_k|b_v|b_o1|W_o2
    float sSc[TE][4];                    // 2048 B
    float sAttn[TE][4];                  // 2048 B
    float sPart[TE][2];                  // 1024 B
    int   sSrc[TE], sTgt[TE], sRel[TE];  // 1536 B
};

// sHid element address (row, k) -> short index
__device__ __forceinline__ int shid_idx(int row, int k) {
    return (((k >> 3) * 128 + row) << 3) + (k & 7);
}

// A-fragment load straight from a node row (bf16 table or fp32 fallback).
template <bool GBF16>
__device__ __forceinline__ bf16x8 loadA8(const void* row, int off) {
    if (GBF16) {
        return *(const bf16x8*)((const unsigned short*)row + off);
    } else {
        const float* p = (const float*)row + off;
        float4 f0 = *(const float4*)p;
        float4 f1 = *(const float4*)(p + 4);
        union { unsigned short us[8]; bf16x8 v; } pk;
        pk.us[0] = f32_to_bf16(f0.x); pk.us[1] = f32_to_bf16(f0.y);
        pk.us[2] = f32_to_bf16(f0.z); pk.us[3] = f32_to_bf16(f0.w);
        pk.us[4] = f32_to_bf16(f1.x); pk.us[5] = f32_to_bf16(f1.y);
        pk.us[6] = f32_to_bf16(f1.z); pk.us[7] = f32_to_bf16(f1.w);
        return pk.v;
    }
}

// ---------------------------------------------------------------------------
// Fused pipeline, 32x32x16 MFMA. Block = 128 edges, 512 threads = 8 waves.
// Wave w: rt=w>>1 (rows 32rt..+31), cg2=w&1 (cols 64cg2..+63).
//   A-frag: lane l -> A[m = l&31][k = (l>>5)*8 + j]
//   B-frag: lane l -> B[k = (l>>5)*8 + j][n = l&31]
//   C/D:    lane l, reg r -> row = (r&3) + 8*(r>>2) + 4*(l>>5), col = l&31
//
// R7 structure: NO LDS staging, NO barriers inside GEMM loops, NO vmcnt
// drains. A-fragments (node gathers, long latency) roll through a period-4
// register buffer with distance-3 prefetch; B-fragments (L2-hot weight
// tables, already in fragment order) roll through a period-2 buffer.
// K/V/O weight fragments are prefetched into registers BEFORE the preceding
// lgkmcnt-only phase barrier, so their latency hides under epilogues.
// ---------------------------------------------------------------------------
template <bool F32, bool GBF16>
__device__ void fused_body(
    Smem& sm,
    const void* gsrc, const int* edgeIdx, const int* relType,
    const unsigned short* WTe, const unsigned short* WTk,
    const unsigned short* WTv, const unsigned short* WTo1,
    const void* b_edge, const void* b_k, const void* b_v,
    const void* b_o1, const void* W_o2, const void* b_o2,
    const float* Qtab, void* outp, int E)
{
    const int t   = threadIdx.x;
    const int l   = t & 63;
    const int w   = t >> 6;          // 0..7
    const int c   = l & 31;
    const int h5  = l >> 5;
    const int rt  = w >> 1;          // 0..3  row tile
    const int cg2 = w & 1;           // 0..1  col tile
    const int bs  = blockIdx.x * TE;
    const int aRow = 32 * rt + c;

    // ---- preamble ----
    if (t < TE) {
        int e = bs + t;
        if (e >= E) e = E - 1;
        if (e < 0)  e = 0;
        sm.sSrc[t] = edgeIdx[e];
        sm.sTgt[t] = edgeIdx[E + e];
        int r = relType[e];
        if (r < 0) r = 0;
        if (r >= NREL) r = NREL - 1;
        sm.sRel[t] = r;
    }
    for (int i = t; i < 5 * HID; i += 512) {
        int which = i >> 7, j = i & (HID - 1);
        float v = (which == 0) ? ldx<F32>(b_edge, j)
                : (which == 1) ? ldx<F32>(b_k, j)
                : (which == 2) ? ldx<F32>(b_v, j)
                : (which == 3) ? ldx<F32>(b_o1, j)
                               : ldx<F32>(W_o2, j);
        sm.sBias[i] = v;
    }
    for (int i = t; i < NREL * HID; i += 512)
        sm.sQf[i] = Qtab[i];
    barrier_lgkm();

    // Per-lane node-row pointers for this lane's A-row.
    const void* rowSrc;
    const void* rowTgt;
    if (GBF16) {
        rowSrc = (const void*)((const unsigned short*)gsrc + (size_t)sm.sSrc[aRow] * EMB);
        rowTgt = (const void*)((const unsigned short*)gsrc + (size_t)sm.sTgt[aRow] * EMB);
    } else {
        rowSrc = (const void*)((const float*)gsrc + (size_t)sm.sSrc[aRow] * EMB);
        rowTgt = (const void*)((const float*)gsrc + (size_t)sm.sTgt[aRow] * EMB);
    }

    const int bu = (h5 * 128 + 64 * cg2 + c) * 8;   // lane part of B short-offset

    #define LOAD_A(kc, s) \
        loadA8<GBF16>(((kc) < 8) ? rowSrc : rowTgt, ((kc) & 7) * 32 + (s) * 16 + h5 * 8)
    #define LDB(WT, kc, s, ct) \
        (*(const bf16x8*)((WT) + bu + (kc) * 4096 + (s) * 2048 + (ct) * 256))

    // ---- GEMM1: hid = relu([src|tgt] @ W_edge + b_edge), K=512, 16 chunks ----
    // Rolling register pipeline: A period-4 / distance-3, B period-2.
    f32x16 acc[2];
    acc[0] = (f32x16)(0.0f); acc[1] = (f32x16)(0.0f);
    {
        bf16x8 aR[4][2];
        bf16x8 bR[2][2][2];
        #pragma unroll
        for (int p = 0; p < 3; ++p) {
            aR[p][0] = LOAD_A(p, 0);
            aR[p][1] = LOAD_A(p, 1);
        }
        #pragma unroll
        for (int p = 0; p < 2; ++p)
            #pragma unroll
            for (int s = 0; s < 2; ++s)
                #pragma unroll
                for (int ct = 0; ct < 2; ++ct)
                    bR[p][s][ct] = LDB(WTe, p, s, ct);
        #pragma unroll
        for (int kc = 0; kc < 16; ++kc) {
            if (kc < 13) {                      // A(kc+3) -> slot (kc+3)&3
                aR[(kc + 3) & 3][0] = LOAD_A(kc + 3, 0);
                aR[(kc + 3) & 3][1] = LOAD_A(kc + 3, 1);
            }
            #pragma unroll
            for (int s = 0; s < 2; ++s)
                #pragma unroll
                for (int ct = 0; ct < 2; ++ct)
                    acc[ct] = __builtin_amdgcn_mfma_f32_32x32x16_bf16(
                        aR[kc & 3][s], bR[kc & 1][s][ct], acc[ct], 0, 0, 0);
            if (kc < 14) {                      // B(kc+2) -> just-freed slot kc&1
                #pragma unroll
                for (int s = 0; s < 2; ++s)
                    #pragma unroll
                    for (int ct = 0; ct < 2; ++ct)
                        bR[kc & 1][s][ct] = LDB(WTe, kc + 2, s, ct);
            }
        }
    }

    // Prefetch K-GEMM weight fragments NOW; latency hides under the epilogue
    // and the phase barrier (lgkmcnt-only, so these stay in flight).
    bf16x8 bK[4][2][2];
    #pragma unroll
    for (int kc = 0; kc < 4; ++kc)
        #pragma unroll
        for (int s = 0; s < 2; ++s)
            #pragma unroll
            for (int ct = 0; ct < 2; ++ct)
                bK[kc][s][ct] = LDB(WTk, kc, s, ct);

    {   // epilogue: + b_edge, relu -> sHid (bf16, fragment order)
        #pragma unroll
        for (int ct = 0; ct < 2; ++ct) {
            int col = 64 * cg2 + 32 * ct + c;
            float bb = sm.sBias[col];
            #pragma unroll
            for (int r = 0; r < 16; ++r) {
                int erow = 32 * rt + (r & 3) + 8 * (r >> 2) + 4 * h5;
                sm.sHid[shid_idx(erow, col)] = f32_to_bf16(fmaxf(acc[ct][r] + bb, 0.f));
            }
        }
    }
    barrier_lgkm();                      // sHid visible to all waves

    // ---- K GEMM: K=128, 4 chunks, A from sHid, B pre-fetched in regs ----
    f32x16 kacc[2];
    kacc[0] = (f32x16)(0.0f); kacc[1] = (f32x16)(0.0f);
    #pragma unroll
    for (int kc = 0; kc < 4; ++kc)
        #pragma unroll
        for (int s = 0; s < 2; ++s) {
            bf16x8 a = *(const bf16x8*)((const char*)sm.sHid +
                         (((kc * 4 + s * 2 + h5) * 128 + aRow) << 4));
            #pragma unroll
            for (int ct = 0; ct < 2; ++ct)
                kacc[ct] = __builtin_amdgcn_mfma_f32_32x32x16_bf16(
                    a, bK[kc][s][ct], kacc[ct], 0, 0, 0);
        }

    // Prefetch V-GEMM weights; hides under the score/softmax phases.
    bf16x8 bV[4][2][2];
    #pragma unroll
    for (int kc = 0; kc < 4; ++kc)
        #pragma unroll
        for (int s = 0; s < 2; ++s)
            #pragma unroll
            for (int ct = 0; ct < 2; ++ct)
                bV[kc][s][ct] = LDB(WTv, kc, s, ct);

    // ---- scores[e][h] = sum_col Q[rel][col]*(K+bk)[e][col] / sqrt(32) ----
    {
        float ps[2][16];
        #pragma unroll
        for (int ct = 0; ct < 2; ++ct) {
            int col = 64 * cg2 + 32 * ct + c;
            float bk = sm.sBias[HID + col];
            #pragma unroll
            for (int r = 0; r < 16; ++r) {
                int erow = 32 * rt + (r & 3) + 8 * (r >> 2) + 4 * h5;
                ps[ct][r] = (kacc[ct][r] + bk) * sm.sQf[sm.sRel[erow] * HID + col];
            }
        }
        #pragma unroll
        for (int m = 1; m < 32; m <<= 1)
            #pragma unroll
            for (int ct = 0; ct < 2; ++ct)
                #pragma unroll
                for (int r = 0; r < 16; ++r)
                    ps[ct][r] += __shfl_xor(ps[ct][r], m, 64);
        if (c == 0) {
            const float inv = 0.17677669529663687f;   // 1/sqrt(32)
            #pragma unroll
            for (int ct = 0; ct < 2; ++ct) {
                int head = 2 * cg2 + ct;
                #pragma unroll
                for (int r = 0; r < 16; ++r) {
                    int erow = 32 * rt + (r & 3) + 8 * (r >> 2) + 4 * h5;
                    sm.sSc[erow][head] = ps[ct][r] * inv;
                }
            }
        }
    }
    barrier_lgkm();
    if (t < TE) {   // softmax over 4 heads
        float s0 = sm.sSc[t][0], s1 = sm.sSc[t][1];
        float s2 = sm.sSc[t][2], s3 = sm.sSc[t][3];
        float m = fmaxf(fmaxf(s0, s1), fmaxf(s2, s3));
        float e0 = expf(s0 - m), e1 = expf(s1 - m);
        float e2 = expf(s2 - m), e3 = expf(s3 - m);
        float den = e0 + e1 + e2 + e3;
        sm.sAttn[t][0] = e0 / den; sm.sAttn[t][1] = e1 / den;
        sm.sAttn[t][2] = e2 / den; sm.sAttn[t][3] = e3 / den;
    }
    barrier_lgkm();

    // ---- V GEMM (A from sHid, B pre-fetched) ----
    f32x16 vacc[2];
    vacc[0] = (f32x16)(0.0f); vacc[1] = (f32x16)(0.0f);
    #pragma unroll
    for (int kc = 0; kc < 4; ++kc)
        #pragma unroll
        for (int s = 0; s < 2; ++s) {
            bf16x8 a = *(const bf16x8*)((const char*)sm.sHid +
                         (((kc * 4 + s * 2 + h5) * 128 + aRow) << 4));
            #pragma unroll
            for (int ct = 0; ct < 2; ++ct)
                vacc[ct] = __builtin_amdgcn_mfma_f32_32x32x16_bf16(
                    a, bV[kc][s][ct], vacc[ct], 0, 0, 0);
        }

    // Prefetch O-GEMM weights; hides under attend + barrier.
    bf16x8 bO[4][2][2];
    #pragma unroll
    for (int kc = 0; kc < 4; ++kc)
        #pragma unroll
        for (int s = 0; s < 2; ++s)
            #pragma unroll
            for (int ct = 0; ct < 2; ++ct)
                bO[kc][s][ct] = LDB(WTo1, kc, s, ct);

    barrier_lgkm();                      // all waves' V-reads of sHid complete

    // ---- attend + residual (in-place on sHid; quadrant-owned writes) ----
    {
        #pragma unroll
        for (int ct = 0; ct < 2; ++ct) {
            int col  = 64 * cg2 + 32 * ct + c;
            int head = 2 * cg2 + ct;
            float bv = sm.sBias[2 * HID + col];
            #pragma unroll
            for (int r = 0; r < 16; ++r) {
                int erow = 32 * rt + (r & 3) + 8 * (r >> 2) + 4 * h5;
                float at = sm.sAttn[erow][head];
                int   si = shid_idx(erow, col);
                float hv = bf16_to_f32(sm.sHid[si]);
                sm.sHid[si] = f32_to_bf16(at * (vacc[ct][r] + bv) + hv);
            }
        }
    }
    barrier_lgkm();                      // updated sHid visible

    // ---- GEMM3 (A from sHid, B pre-fetched) + final dot with W_o2 ----
    f32x16 oacc[2];
    oacc[0] = (f32x16)(0.0f); oacc[1] = (f32x16)(0.0f);
    #pragma unroll
    for (int kc = 0; kc < 4; ++kc)
        #pragma unroll
        for (int s = 0; s < 2; ++s) {
            bf16x8 a = *(const bf16x8*)((const char*)sm.sHid +
                         (((kc * 4 + s * 2 + h5) * 128 + aRow) << 4));
            #pragma unroll
            for (int ct = 0; ct < 2; ++ct)
                oacc[ct] = __builtin_amdgcn_mfma_f32_32x32x16_bf16(
                    a, bO[kc][s][ct], oacc[ct], 0, 0, 0);
        }
    {
        float pr[16];
        #pragma unroll
        for (int r = 0; r < 16; ++r) pr[r] = 0.f;
        #pragma unroll
        for (int ct = 0; ct < 2; ++ct) {
            int col = 64 * cg2 + 32 * ct + c;
            float bo = sm.sBias[3 * HID + col];
            float wo = sm.sBias[4 * HID + col];
            #pragma unroll
            for (int r = 0; r < 16; ++r)
                pr[r] += fmaxf(oacc[ct][r] + bo, 0.f) * wo;
        }
        #pragma unroll
        for (int m = 1; m < 32; m <<= 1)
            #pragma unroll
            for (int r = 0; r < 16; ++r)
                pr[r] += __shfl_xor(pr[r], m, 64);
        if (c == 0) {
            #pragma unroll
            for (int r = 0; r < 16; ++r) {
                int erow = 32 * rt + (r & 3) + 8 * (r >> 2) + 4 * h5;
                sm.sPart[erow][cg2] = pr[r];
            }
        }
    }
    barrier_lgkm();
    if (t < TE) {
        int ge = bs + t;
        if (ge < E) {
            float val = sm.sPart[t][0] + sm.sPart[t][1] + ldx<F32>(b_o2, 0);
            // F32 path writes fp32 (round-10 lesson: output buffer is fp32).
            if (F32) ((float*)outp)[ge] = val;
            else     ((unsigned short*)outp)[ge] = f32_to_bf16(val);
        }
    }

    #undef LOAD_A
    #undef LDB
}

__global__ __launch_bounds__(512, 4) void RelationAttentionMLPHead_10539849744626_kernel(
    const void* nodeEmb, const unsigned short* nodeBf16, int useConv,
    const int* edgeIdx, const int* relType,
    const unsigned short* WTe, const unsigned short* WTk,
    const unsigned short* WTv, const unsigned short* WTo1,
    const void* b_edge, const void* b_k, const void* b_v,
    const void* b_o1, const void* W_o2, const void* b_o2,
    const float* Qtab, void* outp, int E)
{
    __shared__ Smem sm;     // single allocation shared by all instantiations
    if (detect_f32(nodeEmb)) {
        if (useConv)
            fused_body<true, true >(sm, nodeBf16, edgeIdx, relType, WTe, WTk, WTv, WTo1,
                                    b_edge, b_k, b_v, b_o1, W_o2, b_o2, Qtab, outp, E);
        else
            fused_body<true, false>(sm, nodeEmb, edgeIdx, relType, WTe, WTk, WTv, WTo1,
                                    b_edge, b_k, b_v, b_o1, W_o2, b_o2, Qtab, outp, E);
    } else {
        // input already bf16: gather straight from the input table
        fused_body<false, true>(sm, nodeEmb, edgeIdx, relType, WTe, WTk, WTv, WTo1,
                                b_edge, b_k, b_v, b_o1, W_o2, b_o2, Qtab, outp, E);
    }
}

extern "C" void kernel_launch(void* const* d_in, const int* in_sizes, int n_in,
                              void* d_out, int out_size, void* d_ws, size_t ws_size,
                              hipStream_t stream) {
    (void)n_in;

    const void* nodeEmb = d_in[0];
    const int*  edgeIdx = (const int*)d_in[1];
    const int*  relType = (const int*)d_in[2];
    const void* rel_emb = d_in[3];
    const void* W_edge  = d_in[4];
    const void* b_edge  = d_in[5];
    const void* W_q     = d_in[6];
    const void* b_q     = d_in[7];
    const void* W_k     = d_in[8];
    const void* b_k     = d_in[9];
    const void* W_v     = d_in[10];
    const void* b_v     = d_in[11];
    const void* W_o1    = d_in[12];
    const void* b_o1    = d_in[13];
    const void* W_o2    = d_in[14];
    const void* b_o2    = d_in[15];

    int E = out_size;
    if (E <= 0) E = in_sizes ? in_sizes[2] : 0;
    if (E <= 0) E = 500000;

    unsigned long long nodeElems =
        (in_sizes && in_sizes[0] > 0) ? (unsigned long long)in_sizes[0] : 25600000ull;

    // d_ws layout (recomputed every launch; graph-safe)
    char* ws = (char*)d_ws;
    float*          Qtab     = (float*)ws;                      // 5120 B
    unsigned short* WTe      = (unsigned short*)(ws + 8192);    // 131072 B
    unsigned short* WTk      = (unsigned short*)(ws + 139264);  // 32768 B
    unsigned short* WTv      = (unsigned short*)(ws + 172032);  // 32768 B
    unsigned short* WTo1     = (unsigned short*)(ws + 204800);  // 32768 B
    unsigned short* nodeBf16 = (unsigned short*)(ws + 237568);  // nodeElems*2 B

    size_t need = 237568ull + nodeElems * 2ull;
    int useConv = (ws_size >= need) ? 1 : 0;
    int convBlocks = useConv ? (int)((nodeElems + 2047ull) / 2048ull) : 0;

    prep_kernel<<<convBlocks + 449, 256, 0, stream>>>(
        nodeEmb, W_edge, W_k, W_v, W_o1, rel_emb, W_q, b_q,
        WTe, WTk, WTv, WTo1, Qtab, nodeBf16, convBlocks, nodeElems);

    int grid = (E + TE - 1) / TE;
    if (grid < 1) grid = 1;

    RelationAttentionMLPHead_10539849744626_kernel<<<grid, 512, 0, stream>>>(
        nodeEmb, nodeBf16, useConv, edgeIdx, relType, WTe, WTk, WTv, WTo1,
        b_edge, b_k, b_v, b_o1, W_o2, b_o2, Qtab, d_out, E);
}

// Round 8
// 546.819 us; speedup vs baseline: 1.5032x; 1.0153x over previous
//
#include <hip/hip_runtime.h>

#define EMB   256
#define HID   128
#define RELD  64
#define NREL  10
#define TE    128

typedef __attribute__((ext_vector_type(8)))  short bf16x8;
typedef __attribute__((ext_vector_type(16))) float f32x16;

__device__ __forceinline__ float bf16_to_f32(unsigned short u) {
    union { unsigned int i; float f; } v;
    v.i = ((unsigned int)u) << 16;
    return v.f;
}

__device__ __forceinline__ unsigned short f32_to_bf16(float x) {
    union { unsigned int i; float f; } v;
    v.f = x;
    unsigned int b = v.i;
    unsigned int rounded = b + 0x7fffu + ((b >> 16) & 1u);   // round-nearest-even
    return (unsigned short)(rounded >> 16);
}

template <bool F32>
__device__ __forceinline__ float ldx(const void* p, size_t i) {
    if (F32) return ((const float*)p)[i];
    return bf16_to_f32(((const unsigned short*)p)[i]);
}

// In-kernel parallel dtype detect (validated rounds 7-12: fp32 inputs -> true).
__device__ __forceinline__ bool detect_f32(const void* nodeEmb) {
    const float* f = (const float*)nodeEmb;
    float x = f[(threadIdx.x & 63) * 997];
    bool sane = isfinite(x) && fabsf(x) < 1.0e6f;
    unsigned long long m = __ballot(sane);
    return __popcll(m) >= 48;
}

// Register-free async global->LDS (16B per lane). LDS dest must be the
// wave-uniform base; HW adds lane*16.
__device__ __forceinline__ void gload16(const void* g, void* l) {
    __builtin_amdgcn_global_load_lds(
        (const __attribute__((address_space(1))) unsigned int*)g,
        (__attribute__((address_space(3))) unsigned int*)l, 16, 0, 0);
}

// ---------------------------------------------------------------------------
// Prep kernel — R8: node-table conversion REMOVED (R6/R7 showed main-kernel
// time is byte-insensitive in this range; the 153 MB conversion pass was
// ~160 us of pure overhead every launch). 449 blocks total:
//   blocks [0, 448) : weights -> bf16 in MFMA-FRAGMENT ORDER: per K-chunk
//                     (32 k), 512 16-B units, unit g holds
//                     W[kc*32 + (g>>7)*8 .. +7][g&127].
//   block  448      : per-relation Q table (10x128 fp32)
// ---------------------------------------------------------------------------
template <bool F32>
__device__ void prep_body(int vb, const void* W_edge, const void* W_k,
                          const void* W_v, const void* W_o1, const void* rel_emb,
                          const void* W_q, const void* b_q,
                          unsigned short* WTe, unsigned short* WTk,
                          unsigned short* WTv, unsigned short* WTo1, float* Qtab)
{
    if (vb < 448) {
        int idx = vb * 256 + threadIdx.x;             // 0 .. 114687
        if (idx < 65536) {                            // W_edge: 16 chunks x 4096
            int kc = idx >> 12, e = idx & 4095;
            int g = e >> 3, j = e & 7;
            int col = g & 127, kg = g >> 7;
            int k = kc * 32 + kg * 8 + j;
            WTe[idx] = f32_to_bf16(ldx<F32>(W_edge, (size_t)k * HID + col));
        } else if (idx < 65536 + 16384) {             // W_k: 4 chunks x 4096
            int i = idx - 65536;
            int kc = i >> 12, e = i & 4095;
            int g = e >> 3, j = e & 7;
            int col = g & 127, kg = (g >> 7) & 3;
            int k = kc * 32 + kg * 8 + j;
            WTk[i] = f32_to_bf16(ldx<F32>(W_k, (size_t)k * HID + col));
        } else if (idx < 65536 + 2 * 16384) {
            int i = idx - 65536 - 16384;
            int kc = i >> 12, e = i & 4095;
            int g = e >> 3, j = e & 7;
            int col = g & 127, kg = (g >> 7) & 3;
            int k = kc * 32 + kg * 8 + j;
            WTv[i] = f32_to_bf16(ldx<F32>(W_v, (size_t)k * HID + col));
        } else {
            int i = idx - 65536 - 2 * 16384;
            int kc = i >> 12, e = i & 4095;
            int g = e >> 3, j = e & 7;
            int col = g & 127, kg = (g >> 7) & 3;
            int k = kc * 32 + kg * 8 + j;
            WTo1[i] = f32_to_bf16(ldx<F32>(W_o1, (size_t)k * HID + col));
        }
    } else {
        const int t = threadIdx.x;
        const int c = t & (HID - 1);
        const int h = t >> 7;
        for (int r = h; r < NREL; r += 2) {
            float acc = 0.f;
            for (int d = 0; d < RELD; ++d)
                acc += ldx<F32>(rel_emb, r * RELD + d) * ldx<F32>(W_q, (size_t)d * HID + c);
            Qtab[r * HID + c] = acc + ldx<F32>(b_q, c);
        }
    }
}

__global__ void prep_kernel(const void* nodeEmb,
                            const void* W_edge, const void* W_k, const void* W_v,
                            const void* W_o1, const void* rel_emb, const void* W_q,
                            const void* b_q,
                            unsigned short* WTe, unsigned short* WTk,
                            unsigned short* WTv, unsigned short* WTo1, float* Qtab)
{
    bool f32 = detect_f32(nodeEmb);
    int b = blockIdx.x;
    if (f32) prep_body<true >(b, W_edge, W_k, W_v, W_o1, rel_emb, W_q, b_q,
                              WTe, WTk, WTv, WTo1, Qtab);
    else     prep_body<false>(b, W_edge, W_k, W_v, W_o1, rel_emb, W_q, b_q,
                              WTe, WTk, WTv, WTo1, Qtab);
}

// ---------------------------------------------------------------------------
// Shared memory, ~80 KB -> 2 blocks/CU (16 waves). All MFMA-side tiles are in
// FRAGMENT ORDER (unit u = 16B):
//   SA chunk:  u = s*256 + h5*128 + row       (A, 128 rows x 32 k)
//   SB chunk:  u = (s*2+h5)*128 + col         (B, 32 k x 128 cols, = WT layout)
//   sHid:      u = kg*128 + row, kg = k>>3    (128 rows x 128 k)
// global_load_lds's linear lane->LDS mapping AND the ds_read_b128 fragment
// reads are both conflict-free without swizzles.
// ---------------------------------------------------------------------------
struct __align__(16) Smem {
    unsigned short sHid[16 * 128 * 8];   // 32768 B
    unsigned short SA[2][4096];          // 16384 B: double-buffered A chunk
    unsigned short SB[2][4096];          // 16384 B: double-buffered B chunk
    float sQf[NREL * HID];               // 5120 B
    float sBias[5 * HID];                // 2560 B: b_edge|b_k|b_v|b_o1|W_o2
    float sSc[TE][4];                    // 2048 B
    float sAttn[TE][4];                  // 2048 B
    float sPart[TE][2];                  // 1024 B
    int   sSrc[TE], sTgt[TE], sRel[TE];  // 1536 B
};                                       // total 79872 B

// sHid element address (row, k) -> short index
__device__ __forceinline__ int shid_idx(int row, int k) {
    return (((k >> 3) * 128 + row) << 3) + (k & 7);
}

// ---------------------------------------------------------------------------
// Fused pipeline, 32x32x16 MFMA. Block = 128 edges, 512 threads = 8 waves.
// Wave w: rt=w>>1 (rows 32rt..+31), cg2=w&1 (cols 64cg2..+63).
//   A-frag: lane l -> A[m = l&31][k = (l>>5)*8 + j]
//   B-frag: lane l -> B[k = (l>>5)*8 + j][n = l&31]
//   C/D:    lane l, reg r -> row = (r&3) + 8*(r>>2) + 4*(l>>5), col = l&31
// Staging: per 32-k chunk, double-buffered, one barrier per chunk.
// R8: A gathers fp32 node rows DIRECTLY (reg-staged float4x2 -> bf16 -> LDS);
// no pre-converted table, no conversion prep pass.
// ---------------------------------------------------------------------------
template <bool F32, bool GBF16>
__device__ void fused_body(
    Smem& sm,
    const void* gsrc, const int* edgeIdx, const int* relType,
    const unsigned short* WTe, const unsigned short* WTk,
    const unsigned short* WTv, const unsigned short* WTo1,
    const void* b_edge, const void* b_k, const void* b_v,
    const void* b_o1, const void* W_o2, const void* b_o2,
    const float* Qtab, void* outp, int E)
{
    const int t   = threadIdx.x;
    const int l   = t & 63;
    const int w   = t >> 6;          // 0..7
    const int c   = l & 31;
    const int h5  = l >> 5;
    const int rt  = w >> 1;          // 0..3  row tile
    const int cg2 = w & 1;           // 0..1  col tile
    const int bs  = blockIdx.x * TE;
    const int aRow = 32 * rt + c;

    // ---- preamble ----
    if (t < TE) {
        int e = bs + t;
        if (e >= E) e = E - 1;
        if (e < 0)  e = 0;
        sm.sSrc[t] = edgeIdx[e];
        sm.sTgt[t] = edgeIdx[E + e];
        int r = relType[e];
        if (r < 0) r = 0;
        if (r >= NREL) r = NREL - 1;
        sm.sRel[t] = r;
    }
    for (int i = t; i < 5 * HID; i += 512) {
        int which = i >> 7, j = i & (HID - 1);
        float v = (which == 0) ? ldx<F32>(b_edge, j)
                : (which == 1) ? ldx<F32>(b_k, j)
                : (which == 2) ? ldx<F32>(b_v, j)
                : (which == 3) ? ldx<F32>(b_o1, j)
                               : ldx<F32>(W_o2, j);
        sm.sBias[i] = v;
    }
    for (int i = t; i < NREL * HID; i += 512)
        sm.sQf[i] = Qtab[i];
    __syncthreads();

    // staging role of this thread: unit t = (s, h5, row)
    const int    stS   = t >> 8;          // 0..1
    const int    stH5  = (t >> 7) & 1;
    const int    stRow = t & 127;
    const size_t rowOffS = (size_t)sm.sSrc[stRow] * EMB;
    const size_t rowOffT = (size_t)sm.sTgt[stRow] * EMB;
    const int    colSub  = stS * 16 + stH5 * 8;     // element offset in 32-chunk
    char* const  ldsWaveA0 = (char*)sm.SA[0] + w * 1024;
    char* const  ldsWaveA1 = (char*)sm.SA[1] + w * 1024;
    char* const  ldsWaveB0 = (char*)sm.SB[0] + w * 1024;
    char* const  ldsWaveB1 = (char*)sm.SB[1] + w * 1024;

    #define STAGE_A(kc, buf)                                                     \
    {                                                                            \
        size_t eoff = (((kc) < 8) ? rowOffS : rowOffT)                           \
                      + (size_t)(((kc) & 7) * 32 + colSub);                      \
        if (GBF16) {                                                             \
            gload16((const unsigned short*)gsrc + eoff,                          \
                    (buf) ? ldsWaveA1 : ldsWaveA0);                              \
        } else {                                                                 \
            const float* p_ = (const float*)gsrc + eoff;                         \
            float4 f0_ = *(const float4*)p_;                                     \
            float4 f1_ = *(const float4*)(p_ + 4);                               \
            union { unsigned short us[8]; uint4 v; } pk_;                        \
            pk_.us[0] = f32_to_bf16(f0_.x); pk_.us[1] = f32_to_bf16(f0_.y);      \
            pk_.us[2] = f32_to_bf16(f0_.z); pk_.us[3] = f32_to_bf16(f0_.w);      \
            pk_.us[4] = f32_to_bf16(f1_.x); pk_.us[5] = f32_to_bf16(f1_.y);      \
            pk_.us[6] = f32_to_bf16(f1_.z); pk_.us[7] = f32_to_bf16(f1_.w);      \
            *(uint4*)((char*)sm.SA[(buf)] + t * 16) = pk_.v;                     \
        }                                                                        \
    }

    #define STAGE_B(WT, kc, buf)                                                 \
        gload16((WT) + (kc) * 4096 + t * 8, (buf) ? ldsWaveB1 : ldsWaveB0);

    // MFMA on one staged chunk: A from SA[buf], B from SB[buf]
    #define MFMA_SA(buf, accv)                                                   \
    {                                                                            \
        const char* sa_ = (const char*)sm.SA[(buf)];                             \
        const char* sb_ = (const char*)sm.SB[(buf)];                             \
        _Pragma("unroll")                                                        \
        for (int s_ = 0; s_ < 2; ++s_) {                                         \
            bf16x8 a_ = *(const bf16x8*)(sa_ + ((s_ * 256 + h5 * 128 + aRow) << 4)); \
            _Pragma("unroll")                                                    \
            for (int ct_ = 0; ct_ < 2; ++ct_) {                                  \
                bf16x8 b_ = *(const bf16x8*)                                     \
                    (sb_ + ((s_ * 256 + h5 * 128 + 64 * cg2 + 32 * ct_ + c) << 4)); \
                accv[ct_] = __builtin_amdgcn_mfma_f32_32x32x16_bf16(             \
                                a_, b_, accv[ct_], 0, 0, 0);                     \
            }                                                                    \
        }                                                                        \
    }

    // MFMA with A from sHid (fragment order), B from SB[buf]
    #define MFMA_H(kc, buf, accv)                                                \
    {                                                                            \
        const char* sb_ = (const char*)sm.SB[(buf)];                             \
        _Pragma("unroll")                                                        \
        for (int s_ = 0; s_ < 2; ++s_) {                                         \
            bf16x8 a_ = *(const bf16x8*)((const char*)sm.sHid +                  \
                         ((((kc) * 4 + s_ * 2 + h5) * 128 + aRow) << 4));        \
            _Pragma("unroll")                                                    \
            for (int ct_ = 0; ct_ < 2; ++ct_) {                                  \
                bf16x8 b_ = *(const bf16x8*)                                     \
                    (sb_ + ((s_ * 256 + h5 * 128 + 64 * cg2 + 32 * ct_ + c) << 4)); \
                accv[ct_] = __builtin_amdgcn_mfma_f32_32x32x16_bf16(             \
                                a_, b_, accv[ct_], 0, 0, 0);                     \
            }                                                                    \
        }                                                                        \
    }

    // ---- GEMM1: hid = relu([src|tgt] @ W_edge + b_edge), K=512, 16 chunks ----
    f32x16 acc[2];
    acc[0] = (f32x16)(0.0f); acc[1] = (f32x16)(0.0f);
    STAGE_A(0, 0); STAGE_B(WTe, 0, 0);
    __syncthreads();                     // chunk 0 staged (vmcnt drained)
    #pragma unroll
    for (int kc = 0; kc < 16; ++kc) {
        int buf = kc & 1;
        if (kc < 15) { STAGE_A(kc + 1, buf ^ 1); STAGE_B(WTe, kc + 1, buf ^ 1); }
        MFMA_SA(buf, acc);
        __syncthreads();                 // next chunk staged; buf consumed
    }
    {   // epilogue: + b_edge, relu -> sHid (bf16, fragment order)
        #pragma unroll
        for (int ct = 0; ct < 2; ++ct) {
            int col = 64 * cg2 + 32 * ct + c;
            float bb = sm.sBias[col];
            #pragma unroll
            for (int r = 0; r < 16; ++r) {
                int erow = 32 * rt + (r & 3) + 8 * (r >> 2) + 4 * h5;
                sm.sHid[shid_idx(erow, col)] = f32_to_bf16(fmaxf(acc[ct][r] + bb, 0.f));
            }
        }
    }

    // ---- K GEMM: K=128, 4 chunks, A resident in sHid ----
    f32x16 kacc[2];
    kacc[0] = (f32x16)(0.0f); kacc[1] = (f32x16)(0.0f);
    STAGE_B(WTk, 0, 0);
    __syncthreads();                     // sHid visible + chunk 0 staged
    #pragma unroll
    for (int kc = 0; kc < 4; ++kc) {
        int buf = kc & 1;
        if (kc < 3) STAGE_B(WTk, kc + 1, buf ^ 1);
        MFMA_H(kc, buf, kacc);
        __syncthreads();
    }

    // ---- scores[e][h] = sum_col Q[rel][col]*(K+bk)[e][col] / sqrt(32) ----
    {
        float ps[2][16];
        #pragma unroll
        for (int ct = 0; ct < 2; ++ct) {
            int col = 64 * cg2 + 32 * ct + c;
            float bk = sm.sBias[HID + col];
            #pragma unroll
            for (int r = 0; r < 16; ++r) {
                int erow = 32 * rt + (r & 3) + 8 * (r >> 2) + 4 * h5;
                ps[ct][r] = (kacc[ct][r] + bk) * sm.sQf[sm.sRel[erow] * HID + col];
            }
        }
        #pragma unroll
        for (int m = 1; m < 32; m <<= 1)
            #pragma unroll
            for (int ct = 0; ct < 2; ++ct)
                #pragma unroll
                for (int r = 0; r < 16; ++r)
                    ps[ct][r] += __shfl_xor(ps[ct][r], m, 64);
        if (c == 0) {
            const float inv = 0.17677669529663687f;   // 1/sqrt(32)
            #pragma unroll
            for (int ct = 0; ct < 2; ++ct) {
                int head = 2 * cg2 + ct;
                #pragma unroll
                for (int r = 0; r < 16; ++r) {
                    int erow = 32 * rt + (r & 3) + 8 * (r >> 2) + 4 * h5;
                    sm.sSc[erow][head] = ps[ct][r] * inv;
                }
            }
        }
    }
    __syncthreads();
    if (t < TE) {   // softmax over 4 heads
        float s0 = sm.sSc[t][0], s1 = sm.sSc[t][1];
        float s2 = sm.sSc[t][2], s3 = sm.sSc[t][3];
        float m = fmaxf(fmaxf(s0, s1), fmaxf(s2, s3));
        float e0 = expf(s0 - m), e1 = expf(s1 - m);
        float e2 = expf(s2 - m), e3 = expf(s3 - m);
        float den = e0 + e1 + e2 + e3;
        sm.sAttn[t][0] = e0 / den; sm.sAttn[t][1] = e1 / den;
        sm.sAttn[t][2] = e2 / den; sm.sAttn[t][3] = e3 / den;
    }
    __syncthreads();

    // ---- V GEMM ----
    f32x16 vacc[2];
    vacc[0] = (f32x16)(0.0f); vacc[1] = (f32x16)(0.0f);
    STAGE_B(WTv, 0, 0);
    __syncthreads();
    #pragma unroll
    for (int kc = 0; kc < 4; ++kc) {
        int buf = kc & 1;
        if (kc < 3) STAGE_B(WTv, kc + 1, buf ^ 1);
        MFMA_H(kc, buf, vacc);
        __syncthreads();                 // final iter: fences all sHid A-reads
    }

    // ---- attend + residual (in-place on sHid; element-owner = this lane) ----
    {
        #pragma unroll
        for (int ct = 0; ct < 2; ++ct) {
            int col  = 64 * cg2 + 32 * ct + c;
            int head = 2 * cg2 + ct;
            float bv = sm.sBias[2 * HID + col];
            #pragma unroll
            for (int r = 0; r < 16; ++r) {
                int erow = 32 * rt + (r & 3) + 8 * (r >> 2) + 4 * h5;
                float at = sm.sAttn[erow][head];
                int   si = shid_idx(erow, col);
                float hv = bf16_to_f32(sm.sHid[si]);
                sm.sHid[si] = f32_to_bf16(at * (vacc[ct][r] + bv) + hv);
            }
        }
    }
    __syncthreads();                     // sHid updated for all waves

    // ---- GEMM3 + final dot with W_o2 ----
    f32x16 oacc[2];
    oacc[0] = (f32x16)(0.0f); oacc[1] = (f32x16)(0.0f);
    STAGE_B(WTo1, 0, 0);
    __syncthreads();
    #pragma unroll
    for (int kc = 0; kc < 4; ++kc) {
        int buf = kc & 1;
        if (kc < 3) STAGE_B(WTo1, kc + 1, buf ^ 1);
        MFMA_H(kc, buf, oacc);
        __syncthreads();
    }
    {
        float pr[16];
        #pragma unroll
        for (int r = 0; r < 16; ++r) pr[r] = 0.f;
        #pragma unroll
        for (int ct = 0; ct < 2; ++ct) {
            int col = 64 * cg2 + 32 * ct + c;
            float bo = sm.sBias[3 * HID + col];
            float wo = sm.sBias[4 * HID + col];
            #pragma unroll
            for (int r = 0; r < 16; ++r)
                pr[r] += fmaxf(oacc[ct][r] + bo, 0.f) * wo;
        }
        #pragma unroll
        for (int m = 1; m < 32; m <<= 1)
            #pragma unroll
            for (int r = 0; r < 16; ++r)
                pr[r] += __shfl_xor(pr[r], m, 64);
        if (c == 0) {
            #pragma unroll
            for (int r = 0; r < 16; ++r) {
                int erow = 32 * rt + (r & 3) + 8 * (r >> 2) + 4 * h5;
                sm.sPart[erow][cg2] = pr[r];
            }
        }
    }
    __syncthreads();
    if (t < TE) {
        int ge = bs + t;
        if (ge < E) {
            float val = sm.sPart[t][0] + sm.sPart[t][1] + ldx<F32>(b_o2, 0);
            // F32 path writes fp32 (round-10 lesson: output buffer is fp32).
            if (F32) ((float*)outp)[ge] = val;
            else     ((unsigned short*)outp)[ge] = f32_to_bf16(val);
        }
    }

    #undef STAGE_A
    #undef STAGE_B
    #undef MFMA_SA
    #undef MFMA_H
}

__global__ __launch_bounds__(512, 4) void RelationAttentionMLPHead_10539849744626_kernel(
    const void* nodeEmb, const int* edgeIdx, const int* relType,
    const unsigned short* WTe, const unsigned short* WTk,
    const unsigned short* WTv, const unsigned short* WTo1,
    const void* b_edge, const void* b_k, const void* b_v,
    const void* b_o1, const void* W_o2, const void* b_o2,
    const float* Qtab, void* outp, int E)
{
    __shared__ Smem sm;     // single allocation shared by all instantiations
    if (detect_f32(nodeEmb)) {
        // fp32 node table: gather fp32 rows directly, convert in registers.
        fused_body<true, false>(sm, nodeEmb, edgeIdx, relType, WTe, WTk, WTv, WTo1,
                                b_edge, b_k, b_v, b_o1, W_o2, b_o2, Qtab, outp, E);
    } else {
        // input already bf16: async global_load_lds gather straight from input
        fused_body<false, true>(sm, nodeEmb, edgeIdx, relType, WTe, WTk, WTv, WTo1,
                                b_edge, b_k, b_v, b_o1, W_o2, b_o2, Qtab, outp, E);
    }
}

extern "C" void kernel_launch(void* const* d_in, const int* in_sizes, int n_in,
                              void* d_out, int out_size, void* d_ws, size_t ws_size,
                              hipStream_t stream) {
    (void)n_in; (void)ws_size;

    const void* nodeEmb = d_in[0];
    const int*  edgeIdx = (const int*)d_in[1];
    const int*  relType = (const int*)d_in[2];
    const void* rel_emb = d_in[3];
    const void* W_edge  = d_in[4];
    const void* b_edge  = d_in[5];
    const void* W_q     = d_in[6];
    const void* b_q     = d_in[7];
    const void* W_k     = d_in[8];
    const void* b_k     = d_in[9];
    const void* W_v     = d_in[10];
    const void* b_v     = d_in[11];
    const void* W_o1    = d_in[12];
    const void* b_o1    = d_in[13];
    const void* W_o2    = d_in[14];
    const void* b_o2    = d_in[15];

    int E = out_size;
    if (E <= 0) E = in_sizes ? in_sizes[2] : 0;
    if (E <= 0) E = 500000;

    // d_ws layout (recomputed every launch; graph-safe)
    char* ws = (char*)d_ws;
    float*          Qtab = (float*)ws;                      // 5120 B (8192 rsvd)
    unsigned short* WTe  = (unsigned short*)(ws + 8192);    // 131072 B
    unsigned short* WTk  = (unsigned short*)(ws + 139264);  // 32768 B
    unsigned short* WTv  = (unsigned short*)(ws + 172032);  // 32768 B
    unsigned short* WTo1 = (unsigned short*)(ws + 204800);  // 32768 B

    prep_kernel<<<449, 256, 0, stream>>>(
        nodeEmb, W_edge, W_k, W_v, W_o1, rel_emb, W_q, b_q,
        WTe, WTk, WTv, WTo1, Qtab);

    int grid = (E + TE - 1) / TE;
    if (grid < 1) grid = 1;

    RelationAttentionMLPHead_10539849744626_kernel<<<grid, 512, 0, stream>>>(
        nodeEmb, edgeIdx, relType, WTe, WTk, WTv, WTo1,
        b_edge, b_k, b_v, b_o1, W_o2, b_o2, Qtab, d_out, E);
}

// Round 9
// 435.019 us; speedup vs baseline: 1.8895x; 1.2570x over previous
//
#include <hip/hip_runtime.h>

#define EMB   256
#define HID   128
#define RELD  64
#define NREL  10
#define TE    128

typedef __attribute__((ext_vector_type(8)))  short bf16x8;
typedef __attribute__((ext_vector_type(16))) float f32x16;

__device__ __forceinline__ float bf16_to_f32(unsigned short u) {
    union { unsigned int i; float f; } v;
    v.i = ((unsigned int)u) << 16;
    return v.f;
}

__device__ __forceinline__ unsigned short f32_to_bf16(float x) {
    union { unsigned int i; float f; } v;
    v.f = x;
    unsigned int b = v.i;
    unsigned int rounded = b + 0x7fffu + ((b >> 16) & 1u);   // round-nearest-even
    return (unsigned short)(rounded >> 16);
}

template <bool F32>
__device__ __forceinline__ float ldx(const void* p, size_t i) {
    if (F32) return ((const float*)p)[i];
    return bf16_to_f32(((const unsigned short*)p)[i]);
}

// In-kernel parallel dtype detect (validated rounds 7-12: fp32 inputs -> true).
__device__ __forceinline__ bool detect_f32(const void* nodeEmb) {
    const float* f = (const float*)nodeEmb;
    float x = f[(threadIdx.x & 63) * 997];
    bool sane = isfinite(x) && fabsf(x) < 1.0e6f;
    unsigned long long m = __ballot(sane);
    return __popcll(m) >= 48;
}

// Register-free async global->LDS (16B per lane). LDS dest must be the
// wave-uniform base; HW adds lane*16.
__device__ __forceinline__ void gload16(const void* g, void* l) {
    __builtin_amdgcn_global_load_lds(
        (const __attribute__((address_space(1))) unsigned int*)g,
        (__attribute__((address_space(3))) unsigned int*)l, 16, 0, 0);
}

// ---- T4 counted-vmcnt barrier kit -----------------------------------------
// WAITVL(n): wait until at most n vector-memory ops outstanding (the n newest
// — i.e. the NEXT chunk's in-flight global_load_lds stay in flight), and all
// LDS ops done. Literal immediates only (asm requirement).
#define WAITVL(n) asm volatile("s_waitcnt vmcnt(" #n ") lgkmcnt(0)" ::: "memory")

__device__ __forceinline__ void sbar() {           // raw workgroup barrier,
    __builtin_amdgcn_sched_barrier(0);             // no vmcnt drain
    __builtin_amdgcn_s_barrier();
    __builtin_amdgcn_sched_barrier(0);
}
__device__ __forceinline__ void bar_lds() {        // phase barrier: LDS-visible,
    asm volatile("s_waitcnt lgkmcnt(0)" ::: "memory");  // vmem prefetches survive
    sbar();
}

// ---------------------------------------------------------------------------
// Merged prep kernel (R2 version, conversion RESTORED — R8 A/B showed the
// bf16 table saves ~124 us on main for ~35 us of prep):
//   blocks [0, convBlocks)    : fp32 node table -> bf16 copy
//   blocks [convBlocks, +448) : weights -> bf16 in MFMA-FRAGMENT ORDER
//   block  convBlocks+448     : per-relation Q table (10x128 fp32)
// ---------------------------------------------------------------------------
template <bool F32>
__device__ void prep_body(int vb, const void* W_edge, const void* W_k,
                          const void* W_v, const void* W_o1, const void* rel_emb,
                          const void* W_q, const void* b_q,
                          unsigned short* WTe, unsigned short* WTk,
                          unsigned short* WTv, unsigned short* WTo1, float* Qtab)
{
    if (vb < 448) {
        int idx = vb * 256 + threadIdx.x;             // 0 .. 114687
        if (idx < 65536) {                            // W_edge: 16 chunks x 4096
            int kc = idx >> 12, e = idx & 4095;
            int g = e >> 3, j = e & 7;
            int col = g & 127, kg = g >> 7;
            int k = kc * 32 + kg * 8 + j;
            WTe[idx] = f32_to_bf16(ldx<F32>(W_edge, (size_t)k * HID + col));
        } else if (idx < 65536 + 16384) {             // W_k: 4 chunks x 4096
            int i = idx - 65536;
            int kc = i >> 12, e = i & 4095;
            int g = e >> 3, j = e & 7;
            int col = g & 127, kg = (g >> 7) & 3;
            int k = kc * 32 + kg * 8 + j;
            WTk[i] = f32_to_bf16(ldx<F32>(W_k, (size_t)k * HID + col));
        } else if (idx < 65536 + 2 * 16384) {
            int i = idx - 65536 - 16384;
            int kc = i >> 12, e = i & 4095;
            int g = e >> 3, j = e & 7;
            int col = g & 127, kg = (g >> 7) & 3;
            int k = kc * 32 + kg * 8 + j;
            WTv[i] = f32_to_bf16(ldx<F32>(W_v, (size_t)k * HID + col));
        } else {
            int i = idx - 65536 - 2 * 16384;
            int kc = i >> 12, e = i & 4095;
            int g = e >> 3, j = e & 7;
            int col = g & 127, kg = (g >> 7) & 3;
            int k = kc * 32 + kg * 8 + j;
            WTo1[i] = f32_to_bf16(ldx<F32>(W_o1, (size_t)k * HID + col));
        }
    } else {
        const int t = threadIdx.x;
        const int c = t & (HID - 1);
        const int h = t >> 7;
        for (int r = h; r < NREL; r += 2) {
            float acc = 0.f;
            for (int d = 0; d < RELD; ++d)
                acc += ldx<F32>(rel_emb, r * RELD + d) * ldx<F32>(W_q, (size_t)d * HID + c);
            Qtab[r * HID + c] = acc + ldx<F32>(b_q, c);
        }
    }
}

__global__ void prep_kernel(const void* nodeEmb,
                            const void* W_edge, const void* W_k, const void* W_v,
                            const void* W_o1, const void* rel_emb, const void* W_q,
                            const void* b_q,
                            unsigned short* WTe, unsigned short* WTk,
                            unsigned short* WTv, unsigned short* WTo1, float* Qtab,
                            unsigned short* nodeBf16, int convBlocks,
                            unsigned long long nodeElems)
{
    bool f32 = detect_f32(nodeEmb);
    int b = blockIdx.x;
    if (b < convBlocks) {
        if (!f32) return;                             // bf16 input: no conversion
        unsigned long long i = (unsigned long long)b * 2048ull + threadIdx.x * 8;
        if (i + 8 <= nodeElems) {
            const float* src = (const float*)nodeEmb + i;
            float4 f0 = *(const float4*)src;
            float4 f1 = *(const float4*)(src + 4);
            union { unsigned short us[8]; uint4 v; } pk;
            pk.us[0] = f32_to_bf16(f0.x); pk.us[1] = f32_to_bf16(f0.y);
            pk.us[2] = f32_to_bf16(f0.z); pk.us[3] = f32_to_bf16(f0.w);
            pk.us[4] = f32_to_bf16(f1.x); pk.us[5] = f32_to_bf16(f1.y);
            pk.us[6] = f32_to_bf16(f1.z); pk.us[7] = f32_to_bf16(f1.w);
            *(uint4*)(nodeBf16 + i) = pk.v;
        }
        return;
    }
    b -= convBlocks;
    if (f32) prep_body<true >(b, W_edge, W_k, W_v, W_o1, rel_emb, W_q, b_q,
                              WTe, WTk, WTv, WTo1, Qtab);
    else     prep_body<false>(b, W_edge, W_k, W_v, W_o1, rel_emb, W_q, b_q,
                              WTe, WTk, WTv, WTo1, Qtab);
}

// ---------------------------------------------------------------------------
// Shared memory, ~80 KB -> 2 blocks/CU (16 waves). All MFMA-side tiles in
// FRAGMENT ORDER (unit u = 16B):
//   SA chunk:  u = s*256 + h5*128 + row       (A, 128 rows x 32 k)
//   SB chunk:  u = (s*2+h5)*128 + col         (B, 32 k x 128 cols, = WT layout)
//   sHid:      u = kg*128 + row, kg = k>>3    (128 rows x 128 k)
// ---------------------------------------------------------------------------
struct __align__(16) Smem {
    unsigned short sHid[16 * 128 * 8];   // 32768 B
    unsigned short SA[2][4096];          // 16384 B: double-buffered A chunk
    unsigned short SB[2][4096];          // 16384 B: double-buffered B chunk
    float sQf[NREL * HID];               // 5120 B
    float sBias[5 * HID];                // 2560 B: b_edge|b_k|b_v|b_o1|W_o2
    float sSc[TE][4];                    // 2048 B
    float sAttn[TE][4];                  // 2048 B
    float sPart[TE][2];                  // 1024 B
    int   sSrc[TE], sTgt[TE], sRel[TE];  // 1536 B
};                                       // total 79872 B

// sHid element address (row, k) -> short index
__device__ __forceinline__ int shid_idx(int row, int k) {
    return (((k >> 3) * 128 + row) << 3) + (k & 7);
}

// ---------------------------------------------------------------------------
// Fused pipeline, 32x32x16 MFMA. Block = 128 edges, 512 threads = 8 waves.
// Wave w: rt=w>>1 (rows 32rt..+31), cg2=w&1 (cols 64cg2..+63).
//
// R9 = R2 structure + T4 counted vmcnt. Per chunk iteration:
//   s_waitcnt vmcnt(N) [N = next chunk's in-flight loads, never 0 mid-loop]
//   s_barrier            -> chunk k visible to all waves
//   MFMA(buf)
//   s_barrier            -> buf consumed by all waves (ds_reads drained by
//                           the MFMA data deps before each wave arrives)
//   STAGE(k+2 -> buf)    -> issue into freed buffer; lands ~2 iters later
// Phase boundaries use lgkmcnt-only barriers so the next GEMM's first two
// B-chunk prefetches (issued right after the previous loop) stay in flight.
// ---------------------------------------------------------------------------
template <bool F32, bool GBF16>
__device__ void fused_body(
    Smem& sm,
    const void* gsrc, const int* edgeIdx, const int* relType,
    const unsigned short* WTe, const unsigned short* WTk,
    const unsigned short* WTv, const unsigned short* WTo1,
    const void* b_edge, const void* b_k, const void* b_v,
    const void* b_o1, const void* W_o2, const void* b_o2,
    const float* Qtab, void* outp, int E)
{
    const int t   = threadIdx.x;
    const int l   = t & 63;
    const int w   = t >> 6;          // 0..7
    const int c   = l & 31;
    const int h5  = l >> 5;
    const int rt  = w >> 1;          // 0..3  row tile
    const int cg2 = w & 1;           // 0..1  col tile
    const int bs  = blockIdx.x * TE;
    const int aRow = 32 * rt + c;

    // ---- preamble ----
    if (t < TE) {
        int e = bs + t;
        if (e >= E) e = E - 1;
        if (e < 0)  e = 0;
        sm.sSrc[t] = edgeIdx[e];
        sm.sTgt[t] = edgeIdx[E + e];
        int r = relType[e];
        if (r < 0) r = 0;
        if (r >= NREL) r = NREL - 1;
        sm.sRel[t] = r;
    }
    for (int i = t; i < 5 * HID; i += 512) {
        int which = i >> 7, j = i & (HID - 1);
        float v = (which == 0) ? ldx<F32>(b_edge, j)
                : (which == 1) ? ldx<F32>(b_k, j)
                : (which == 2) ? ldx<F32>(b_v, j)
                : (which == 3) ? ldx<F32>(b_o1, j)
                               : ldx<F32>(W_o2, j);
        sm.sBias[i] = v;
    }
    for (int i = t; i < NREL * HID; i += 512)
        sm.sQf[i] = Qtab[i];
    __syncthreads();

    // staging role of this thread: unit t = (s, h5, row)
    const int    stRow = t & 127;
    const size_t rowOffS = (size_t)sm.sSrc[stRow] * EMB;
    const size_t rowOffT = (size_t)sm.sTgt[stRow] * EMB;
    const int    colSub  = (t >> 8) * 16 + ((t >> 7) & 1) * 8;
    char* const  ldsWaveA0 = (char*)sm.SA[0] + w * 1024;
    char* const  ldsWaveA1 = (char*)sm.SA[1] + w * 1024;
    char* const  ldsWaveB0 = (char*)sm.SB[0] + w * 1024;
    char* const  ldsWaveB1 = (char*)sm.SB[1] + w * 1024;

    #define STAGE_A(kc, buf)                                                     \
    {                                                                            \
        size_t eoff = (((kc) < 8) ? rowOffS : rowOffT)                           \
                      + (size_t)(((kc) & 7) * 32 + colSub);                      \
        if (GBF16) {                                                             \
            gload16((const unsigned short*)gsrc + eoff,                          \
                    (buf) ? ldsWaveA1 : ldsWaveA0);                              \
        } else {                                                                 \
            const float* p_ = (const float*)gsrc + eoff;                         \
            float4 f0_ = *(const float4*)p_;                                     \
            float4 f1_ = *(const float4*)(p_ + 4);                               \
            union { unsigned short us[8]; uint4 v; } pk_;                        \
            pk_.us[0] = f32_to_bf16(f0_.x); pk_.us[1] = f32_to_bf16(f0_.y);      \
            pk_.us[2] = f32_to_bf16(f0_.z); pk_.us[3] = f32_to_bf16(f0_.w);      \
            pk_.us[4] = f32_to_bf16(f1_.x); pk_.us[5] = f32_to_bf16(f1_.y);      \
            pk_.us[6] = f32_to_bf16(f1_.z); pk_.us[7] = f32_to_bf16(f1_.w);      \
            *(uint4*)((char*)sm.SA[(buf)] + t * 16) = pk_.v;                     \
        }                                                                        \
    }

    #define STAGE_B(WT, kc, buf)                                                 \
        gload16((WT) + (kc) * 4096 + t * 8, (buf) ? ldsWaveB1 : ldsWaveB0);

    #define MFMA_SA(buf, accv)                                                   \
    {                                                                            \
        const char* sa_ = (const char*)sm.SA[(buf)];                             \
        const char* sb_ = (const char*)sm.SB[(buf)];                             \
        _Pragma("unroll")                                                        \
        for (int s_ = 0; s_ < 2; ++s_) {                                         \
            bf16x8 a_ = *(const bf16x8*)(sa_ + ((s_ * 256 + h5 * 128 + aRow) << 4)); \
            _Pragma("unroll")                                                    \
            for (int ct_ = 0; ct_ < 2; ++ct_) {                                  \
                bf16x8 b_ = *(const bf16x8*)                                     \
                    (sb_ + ((s_ * 256 + h5 * 128 + 64 * cg2 + 32 * ct_ + c) << 4)); \
                accv[ct_] = __builtin_amdgcn_mfma_f32_32x32x16_bf16(             \
                                a_, b_, accv[ct_], 0, 0, 0);                     \
            }                                                                    \
        }                                                                        \
    }

    #define MFMA_H(kc, buf, accv)                                                \
    {                                                                            \
        const char* sb_ = (const char*)sm.SB[(buf)];                             \
        _Pragma("unroll")                                                        \
        for (int s_ = 0; s_ < 2; ++s_) {                                         \
            bf16x8 a_ = *(const bf16x8*)((const char*)sm.sHid +                  \
                         ((((kc) * 4 + s_ * 2 + h5) * 128 + aRow) << 4));        \
            _Pragma("unroll")                                                    \
            for (int ct_ = 0; ct_ < 2; ++ct_) {                                  \
                bf16x8 b_ = *(const bf16x8*)                                     \
                    (sb_ + ((s_ * 256 + h5 * 128 + 64 * cg2 + 32 * ct_ + c) << 4)); \
                accv[ct_] = __builtin_amdgcn_mfma_f32_32x32x16_bf16(             \
                                a_, b_, accv[ct_], 0, 0, 0);                     \
            }                                                                    \
        }                                                                        \
    }

    // ---- GEMM1: hid = relu([src|tgt] @ W_edge + b_edge), K=512, 16 chunks ----
    f32x16 acc[2];
    acc[0] = (f32x16)(0.0f); acc[1] = (f32x16)(0.0f);
    STAGE_A(0, 0); STAGE_B(WTe, 0, 0);           // 2-deep prologue
    STAGE_A(1, 1); STAGE_B(WTe, 1, 1);
    #pragma unroll
    for (int kc = 0; kc < 16; ++kc) {
        int buf = kc & 1;
        if (kc < 15) { WAITVL(2); } else { WAITVL(0); }   // chunk kc landed
        sbar();
        MFMA_SA(buf, acc);
        sbar();                                   // buf consumed by all waves
        if (kc < 14) { STAGE_A(kc + 2, buf); STAGE_B(WTe, kc + 2, buf); }
    }
    // K-GEMM prefetch (flies across the epilogue + lgkm phase barrier)
    STAGE_B(WTk, 0, 0); STAGE_B(WTk, 1, 1);
    {   // epilogue: + b_edge, relu -> sHid (bf16, fragment order)
        #pragma unroll
        for (int ct = 0; ct < 2; ++ct) {
            int col = 64 * cg2 + 32 * ct + c;
            float bb = sm.sBias[col];
            #pragma unroll
            for (int r = 0; r < 16; ++r) {
                int erow = 32 * rt + (r & 3) + 8 * (r >> 2) + 4 * h5;
                sm.sHid[shid_idx(erow, col)] = f32_to_bf16(fmaxf(acc[ct][r] + bb, 0.f));
            }
        }
    }
    bar_lds();                                    // sHid visible; K loads in flight

    // ---- K GEMM: K=128, 4 chunks ----
    f32x16 kacc[2];
    kacc[0] = (f32x16)(0.0f); kacc[1] = (f32x16)(0.0f);
    #pragma unroll
    for (int kc = 0; kc < 4; ++kc) {
        int buf = kc & 1;
        if (kc < 3) { WAITVL(1); } else { WAITVL(0); }
        sbar();
        MFMA_H(kc, buf, kacc);
        sbar();
        if (kc < 2) STAGE_B(WTk, kc + 2, buf);
    }
    STAGE_B(WTv, 0, 0); STAGE_B(WTv, 1, 1);       // V prefetch across scores/softmax

    // ---- scores[e][h] = sum_col Q[rel][col]*(K+bk)[e][col] / sqrt(32) ----
    {
        float ps[2][16];
        #pragma unroll
        for (int ct = 0; ct < 2; ++ct) {
            int col = 64 * cg2 + 32 * ct + c;
            float bk = sm.sBias[HID + col];
            #pragma unroll
            for (int r = 0; r < 16; ++r) {
                int erow = 32 * rt + (r & 3) + 8 * (r >> 2) + 4 * h5;
                ps[ct][r] = (kacc[ct][r] + bk) * sm.sQf[sm.sRel[erow] * HID + col];
            }
        }
        #pragma unroll
        for (int m = 1; m < 32; m <<= 1)
            #pragma unroll
            for (int ct = 0; ct < 2; ++ct)
                #pragma unroll
                for (int r = 0; r < 16; ++r)
                    ps[ct][r] += __shfl_xor(ps[ct][r], m, 64);
        if (c == 0) {
            const float inv = 0.17677669529663687f;   // 1/sqrt(32)
            #pragma unroll
            for (int ct = 0; ct < 2; ++ct) {
                int head = 2 * cg2 + ct;
                #pragma unroll
                for (int r = 0; r < 16; ++r) {
                    int erow = 32 * rt + (r & 3) + 8 * (r >> 2) + 4 * h5;
                    sm.sSc[erow][head] = ps[ct][r] * inv;
                }
            }
        }
    }
    bar_lds();
    if (t < TE) {   // softmax over 4 heads
        float s0 = sm.sSc[t][0], s1 = sm.sSc[t][1];
        float s2 = sm.sSc[t][2], s3 = sm.sSc[t][3];
        float m = fmaxf(fmaxf(s0, s1), fmaxf(s2, s3));
        float e0 = expf(s0 - m), e1 = expf(s1 - m);
        float e2 = expf(s2 - m), e3 = expf(s3 - m);
        float den = e0 + e1 + e2 + e3;
        sm.sAttn[t][0] = e0 / den; sm.sAttn[t][1] = e1 / den;
        sm.sAttn[t][2] = e2 / den; sm.sAttn[t][3] = e3 / den;
    }
    bar_lds();

    // ---- V GEMM ----
    f32x16 vacc[2];
    vacc[0] = (f32x16)(0.0f); vacc[1] = (f32x16)(0.0f);
    #pragma unroll
    for (int kc = 0; kc < 4; ++kc) {
        int buf = kc & 1;
        if (kc < 3) { WAITVL(1); } else { WAITVL(0); }
        sbar();
        MFMA_H(kc, buf, vacc);
        sbar();
        if (kc < 2) STAGE_B(WTv, kc + 2, buf);
    }
    STAGE_B(WTo1, 0, 0); STAGE_B(WTo1, 1, 1);     // O prefetch across attend

    // ---- attend + residual (in-place on sHid; element-owner = this lane;
    //      all waves' V-GEMM sHid reads completed at the loop's last sbar) ----
    {
        #pragma unroll
        for (int ct = 0; ct < 2; ++ct) {
            int col  = 64 * cg2 + 32 * ct + c;
            int head = 2 * cg2 + ct;
            float bv = sm.sBias[2 * HID + col];
            #pragma unroll
            for (int r = 0; r < 16; ++r) {
                int erow = 32 * rt + (r & 3) + 8 * (r >> 2) + 4 * h5;
                float at = sm.sAttn[erow][head];
                int   si = shid_idx(erow, col);
                float hv = bf16_to_f32(sm.sHid[si]);
                sm.sHid[si] = f32_to_bf16(at * (vacc[ct][r] + bv) + hv);
            }
        }
    }
    bar_lds();                                    // updated sHid visible

    // ---- GEMM3 + final dot with W_o2 ----
    f32x16 oacc[2];
    oacc[0] = (f32x16)(0.0f); oacc[1] = (f32x16)(0.0f);
    #pragma unroll
    for (int kc = 0; kc < 4; ++kc) {
        int buf = kc & 1;
        if (kc < 3) { WAITVL(1); } else { WAITVL(0); }
        sbar();
        MFMA_H(kc, buf, oacc);
        sbar();
        if (kc < 2) STAGE_B(WTo1, kc + 2, buf);
    }
    {
        float pr[16];
        #pragma unroll
        for (int r = 0; r < 16; ++r) pr[r] = 0.f;
        #pragma unroll
        for (int ct = 0; ct < 2; ++ct) {
            int col = 64 * cg2 + 32 * ct + c;
            float bo = sm.sBias[3 * HID + col];
            float wo = sm.sBias[4 * HID + col];
            #pragma unroll
            for (int r = 0; r < 16; ++r)
                pr[r] += fmaxf(oacc[ct][r] + bo, 0.f) * wo;
        }
        #pragma unroll
        for (int m = 1; m < 32; m <<= 1)
            #pragma unroll
            for (int r = 0; r < 16; ++r)
                pr[r] += __shfl_xor(pr[r], m, 64);
        if (c == 0) {
            #pragma unroll
            for (int r = 0; r < 16; ++r) {
                int erow = 32 * rt + (r & 3) + 8 * (r >> 2) + 4 * h5;
                sm.sPart[erow][cg2] = pr[r];
            }
        }
    }
    bar_lds();
    if (t < TE) {
        int ge = bs + t;
        if (ge < E) {
            float val = sm.sPart[t][0] + sm.sPart[t][1] + ldx<F32>(b_o2, 0);
            // F32 path writes fp32 (round-10 lesson: output buffer is fp32).
            if (F32) ((float*)outp)[ge] = val;
            else     ((unsigned short*)outp)[ge] = f32_to_bf16(val);
        }
    }

    #undef STAGE_A
    #undef STAGE_B
    #undef MFMA_SA
    #undef MFMA_H
}

__global__ __launch_bounds__(512, 4) void RelationAttentionMLPHead_10539849744626_kernel(
    const void* nodeEmb, const unsigned short* nodeBf16, int useConv,
    const int* edgeIdx, const int* relType,
    const unsigned short* WTe, const unsigned short* WTk,
    const unsigned short* WTv, const unsigned short* WTo1,
    const void* b_edge, const void* b_k, const void* b_v,
    const void* b_o1, const void* W_o2, const void* b_o2,
    const float* Qtab, void* outp, int E)
{
    __shared__ Smem sm;     // single allocation shared by all instantiations
    if (detect_f32(nodeEmb)) {
        if (useConv)
            fused_body<true, true >(sm, nodeBf16, edgeIdx, relType, WTe, WTk, WTv, WTo1,
                                    b_edge, b_k, b_v, b_o1, W_o2, b_o2, Qtab, outp, E);
        else
            fused_body<true, false>(sm, nodeEmb, edgeIdx, relType, WTe, WTk, WTv, WTo1,
                                    b_edge, b_k, b_v, b_o1, W_o2, b_o2, Qtab, outp, E);
    } else {
        // input already bf16: gather straight from the input table
        fused_body<false, true>(sm, nodeEmb, edgeIdx, relType, WTe, WTk, WTv, WTo1,
                                b_edge, b_k, b_v, b_o1, W_o2, b_o2, Qtab, outp, E);
    }
}

extern "C" void kernel_launch(void* const* d_in, const int* in_sizes, int n_in,
                              void* d_out, int out_size, void* d_ws, size_t ws_size,
                              hipStream_t stream) {
    (void)n_in;

    const void* nodeEmb = d_in[0];
    const int*  edgeIdx = (const int*)d_in[1];
    const int*  relType = (const int*)d_in[2];
    const void* rel_emb = d_in[3];
    const void* W_edge  = d_in[4];
    const void* b_edge  = d_in[5];
    const void* W_q     = d_in[6];
    const void* b_q     = d_in[7];
    const void* W_k     = d_in[8];
    const void* b_k     = d_in[9];
    const void* W_v     = d_in[10];
    const void* b_v     = d_in[11];
    const void* W_o1    = d_in[12];
    const void* b_o1    = d_in[13];
    const void* W_o2    = d_in[14];
    const void* b_o2    = d_in[15];

    int E = out_size;
    if (E <= 0) E = in_sizes ? in_sizes[2] : 0;
    if (E <= 0) E = 500000;

    unsigned long long nodeElems =
        (in_sizes && in_sizes[0] > 0) ? (unsigned long long)in_sizes[0] : 25600000ull;

    // d_ws layout (recomputed every launch; graph-safe)
    char* ws = (char*)d_ws;
    float*          Qtab     = (float*)ws;                      // 5120 B
    unsigned short* WTe      = (unsigned short*)(ws + 8192);    // 131072 B
    unsigned short* WTk      = (unsigned short*)(ws + 139264);  // 32768 B
    unsigned short* WTv      = (unsigned short*)(ws + 172032);  // 32768 B
    unsigned short* WTo1     = (unsigned short*)(ws + 204800);  // 32768 B
    unsigned short* nodeBf16 = (unsigned short*)(ws + 237568);  // nodeElems*2 B

    size_t need = 237568ull + nodeElems * 2ull;
    int useConv = (ws_size >= need) ? 1 : 0;
    int convBlocks = useConv ? (int)((nodeElems + 2047ull) / 2048ull) : 0;

    prep_kernel<<<convBlocks + 449, 256, 0, stream>>>(
        nodeEmb, W_edge, W_k, W_v, W_o1, rel_emb, W_q, b_q,
        WTe, WTk, WTv, WTo1, Qtab, nodeBf16, convBlocks, nodeElems);

    int grid = (E + TE - 1) / TE;
    if (grid < 1) grid = 1;

    RelationAttentionMLPHead_10539849744626_kernel<<<grid, 512, 0, stream>>>(
        nodeEmb, nodeBf16, useConv, edgeIdx, relType, WTe, WTk, WTv, WTo1,
        b_edge, b_k, b_v, b_o1, W_o2, b_o2, Qtab, d_out, E);
}

// Round 10
// 428.320 us; speedup vs baseline: 1.9191x; 1.0156x over previous
//
#include <hip/hip_runtime.h>

#define EMB   256
#define HID   128
#define RELD  64
#define NREL  10
#define TE    128
#define SHSTR 130   // sHid k-group stride in 16B units (128 + 2 pad: kills the
                    // 8-way bank conflict on epilogue/attend u16 writes)

typedef __attribute__((ext_vector_type(8)))  short bf16x8;
typedef __attribute__((ext_vector_type(16))) float f32x16;

__device__ __forceinline__ float bf16_to_f32(unsigned short u) {
    union { unsigned int i; float f; } v;
    v.i = ((unsigned int)u) << 16;
    return v.f;
}

__device__ __forceinline__ unsigned short f32_to_bf16(float x) {
    union { unsigned int i; float f; } v;
    v.f = x;
    unsigned int b = v.i;
    unsigned int rounded = b + 0x7fffu + ((b >> 16) & 1u);   // round-nearest-even
    return (unsigned short)(rounded >> 16);
}

template <bool F32>
__device__ __forceinline__ float ldx(const void* p, size_t i) {
    if (F32) return ((const float*)p)[i];
    return bf16_to_f32(((const unsigned short*)p)[i]);
}

// In-kernel parallel dtype detect (validated rounds 7-12: fp32 inputs -> true).
__device__ __forceinline__ bool detect_f32(const void* nodeEmb) {
    const float* f = (const float*)nodeEmb;
    float x = f[(threadIdx.x & 63) * 997];
    bool sane = isfinite(x) && fabsf(x) < 1.0e6f;
    unsigned long long m = __ballot(sane);
    return __popcll(m) >= 48;
}

// Register-free async global->LDS (16B per lane). LDS dest must be the
// wave-uniform base; HW adds lane*16.
__device__ __forceinline__ void gload16(const void* g, void* l) {
    __builtin_amdgcn_global_load_lds(
        (const __attribute__((address_space(1))) unsigned int*)g,
        (__attribute__((address_space(3))) unsigned int*)l, 16, 0, 0);
}

// ---- T4 counted-vmcnt barrier kit -----------------------------------------
#define WAITVL(n) asm volatile("s_waitcnt vmcnt(" #n ") lgkmcnt(0)" ::: "memory")

__device__ __forceinline__ void sbar() {           // raw workgroup barrier,
    __builtin_amdgcn_sched_barrier(0);             // no vmcnt drain
    __builtin_amdgcn_s_barrier();
    __builtin_amdgcn_sched_barrier(0);
}
__device__ __forceinline__ void bar_lds() {        // phase barrier: LDS-visible,
    asm volatile("s_waitcnt lgkmcnt(0)" ::: "memory");  // vmem prefetches survive
    sbar();
}

// ---------------------------------------------------------------------------
// Merged prep kernel (conversion kept — R8 A/B: bf16 table saves ~124 us on
// main for ~37 us of prep):
//   blocks [0, convBlocks)    : fp32 node table -> bf16 copy
//   blocks [convBlocks, +448) : weights -> bf16 in MFMA-FRAGMENT ORDER
//   block  convBlocks+448     : per-relation Q table (10x128 fp32)
// ---------------------------------------------------------------------------
template <bool F32>
__device__ void prep_body(int vb, const void* W_edge, const void* W_k,
                          const void* W_v, const void* W_o1, const void* rel_emb,
                          const void* W_q, const void* b_q,
                          unsigned short* WTe, unsigned short* WTk,
                          unsigned short* WTv, unsigned short* WTo1, float* Qtab)
{
    if (vb < 448) {
        int idx = vb * 256 + threadIdx.x;             // 0 .. 114687
        if (idx < 65536) {                            // W_edge: 16 chunks x 4096
            int kc = idx >> 12, e = idx & 4095;
            int g = e >> 3, j = e & 7;
            int col = g & 127, kg = g >> 7;
            int k = kc * 32 + kg * 8 + j;
            WTe[idx] = f32_to_bf16(ldx<F32>(W_edge, (size_t)k * HID + col));
        } else if (idx < 65536 + 16384) {             // W_k: 4 chunks x 4096
            int i = idx - 65536;
            int kc = i >> 12, e = i & 4095;
            int g = e >> 3, j = e & 7;
            int col = g & 127, kg = (g >> 7) & 3;
            int k = kc * 32 + kg * 8 + j;
            WTk[i] = f32_to_bf16(ldx<F32>(W_k, (size_t)k * HID + col));
        } else if (idx < 65536 + 2 * 16384) {
            int i = idx - 65536 - 16384;
            int kc = i >> 12, e = i & 4095;
            int g = e >> 3, j = e & 7;
            int col = g & 127, kg = (g >> 7) & 3;
            int k = kc * 32 + kg * 8 + j;
            WTv[i] = f32_to_bf16(ldx<F32>(W_v, (size_t)k * HID + col));
        } else {
            int i = idx - 65536 - 2 * 16384;
            int kc = i >> 12, e = i & 4095;
            int g = e >> 3, j = e & 7;
            int col = g & 127, kg = (g >> 7) & 3;
            int k = kc * 32 + kg * 8 + j;
            WTo1[i] = f32_to_bf16(ldx<F32>(W_o1, (size_t)k * HID + col));
        }
    } else {
        const int t = threadIdx.x;
        const int c = t & (HID - 1);
        const int h = t >> 7;
        for (int r = h; r < NREL; r += 2) {
            float acc = 0.f;
            for (int d = 0; d < RELD; ++d)
                acc += ldx<F32>(rel_emb, r * RELD + d) * ldx<F32>(W_q, (size_t)d * HID + c);
            Qtab[r * HID + c] = acc + ldx<F32>(b_q, c);
        }
    }
}

__global__ void prep_kernel(const void* nodeEmb,
                            const void* W_edge, const void* W_k, const void* W_v,
                            const void* W_o1, const void* rel_emb, const void* W_q,
                            const void* b_q,
                            unsigned short* WTe, unsigned short* WTk,
                            unsigned short* WTv, unsigned short* WTo1, float* Qtab,
                            unsigned short* nodeBf16, int convBlocks,
                            unsigned long long nodeElems)
{
    bool f32 = detect_f32(nodeEmb);
    int b = blockIdx.x;
    if (b < convBlocks) {
        if (!f32) return;                             // bf16 input: no conversion
        unsigned long long i = (unsigned long long)b * 2048ull + threadIdx.x * 8;
        if (i + 8 <= nodeElems) {
            const float* src = (const float*)nodeEmb + i;
            float4 f0 = *(const float4*)src;
            float4 f1 = *(const float4*)(src + 4);
            union { unsigned short us[8]; uint4 v; } pk;
            pk.us[0] = f32_to_bf16(f0.x); pk.us[1] = f32_to_bf16(f0.y);
            pk.us[2] = f32_to_bf16(f0.z); pk.us[3] = f32_to_bf16(f0.w);
            pk.us[4] = f32_to_bf16(f1.x); pk.us[5] = f32_to_bf16(f1.y);
            pk.us[6] = f32_to_bf16(f1.z); pk.us[7] = f32_to_bf16(f1.w);
            *(uint4*)(nodeBf16 + i) = pk.v;
        }
        return;
    }
    b -= convBlocks;
    if (f32) prep_body<true >(b, W_edge, W_k, W_v, W_o1, rel_emb, W_q, b_q,
                              WTe, WTk, WTv, WTo1, Qtab);
    else     prep_body<false>(b, W_edge, W_k, W_v, W_o1, rel_emb, W_q, b_q,
                              WTe, WTk, WTv, WTo1, Qtab);
}

// ---------------------------------------------------------------------------
// Shared memory, 64000 B -> 2 blocks/CU (16 waves). SA staging GONE (GEMM1 A
// is direct-to-register). sHid in padded fragment order:
//   unit u = kg*SHSTR + row (kg = k>>3)  — pad +2 units/group de-conflicts
//   the u16 epilogue/attend writes (groups land on banks 0/8/16/24).
//   SB chunk: u = (s*2+h5)*128 + col     (B, 32 k x 128 cols, = WT layout)
// ---------------------------------------------------------------------------
struct __align__(16) Smem {
    unsigned short sHid[16 * SHSTR * 8]; // 33280 B
    unsigned short SB[2][4096];          // 16384 B: double-buffered B chunk
    float sQf[NREL * HID];               // 5120 B
    float sBias[5 * HID];                // 2560 B: b_edge|b_k|b_v|b_o1|W_o2
    float sSc[TE][4];                    // 2048 B
    float sAttn[TE][4];                  // 2048 B
    float sPart[TE][2];                  // 1024 B
    int   sSrc[TE], sTgt[TE], sRel[TE];  // 1536 B
};                                       // total 64000 B

// sHid element address (row, k) -> short index
__device__ __forceinline__ int shid_idx(int row, int k) {
    return (((k >> 3) * SHSTR + row) << 3) + (k & 7);
}

// A-fragment load straight from a node row (bf16 table or fp32 fallback).
template <bool GBF16>
__device__ __forceinline__ bf16x8 loadA8(const void* row, int off) {
    if (GBF16) {
        return *(const bf16x8*)((const unsigned short*)row + off);
    } else {
        const float* p = (const float*)row + off;
        float4 f0 = *(const float4*)p;
        float4 f1 = *(const float4*)(p + 4);
        union { unsigned short us[8]; bf16x8 v; } pk;
        pk.us[0] = f32_to_bf16(f0.x); pk.us[1] = f32_to_bf16(f0.y);
        pk.us[2] = f32_to_bf16(f0.z); pk.us[3] = f32_to_bf16(f0.w);
        pk.us[4] = f32_to_bf16(f1.x); pk.us[5] = f32_to_bf16(f1.y);
        pk.us[6] = f32_to_bf16(f1.z); pk.us[7] = f32_to_bf16(f1.w);
        return pk.v;
    }
}

// ---------------------------------------------------------------------------
// Fused pipeline, 32x32x16 MFMA. Block = 128 edges, 512 threads = 8 waves.
// Wave w: rt=w>>1 (rows 32rt..+31), cg2=w&1 (cols 64cg2..+63).
//
// R10 GEMM1: A-fragments DIRECT to registers, rolling depth-4 buffer
// (issue A(k+3) at iter k -> 3-iteration landing window; compiler's dep
// waits cover A, explicit counted WAITVL covers the B global_load_lds).
// B through LDS double-buffer with counted vmcnt (never 0 mid-loop).
// K/V/O loops unchanged from R9 (proven).
// ---------------------------------------------------------------------------
template <bool F32, bool GBF16>
__device__ void fused_body(
    Smem& sm,
    const void* gsrc, const int* edgeIdx, const int* relType,
    const unsigned short* WTe, const unsigned short* WTk,
    const unsigned short* WTv, const unsigned short* WTo1,
    const void* b_edge, const void* b_k, const void* b_v,
    const void* b_o1, const void* W_o2, const void* b_o2,
    const float* Qtab, void* outp, int E)
{
    const int t   = threadIdx.x;
    const int l   = t & 63;
    const int w   = t >> 6;          // 0..7
    const int c   = l & 31;
    const int h5  = l >> 5;
    const int rt  = w >> 1;          // 0..3  row tile
    const int cg2 = w & 1;           // 0..1  col tile
    const int bs  = blockIdx.x * TE;
    const int aRow = 32 * rt + c;

    // ---- preamble ----
    if (t < TE) {
        int e = bs + t;
        if (e >= E) e = E - 1;
        if (e < 0)  e = 0;
        sm.sSrc[t] = edgeIdx[e];
        sm.sTgt[t] = edgeIdx[E + e];
        int r = relType[e];
        if (r < 0) r = 0;
        if (r >= NREL) r = NREL - 1;
        sm.sRel[t] = r;
    }
    for (int i = t; i < 5 * HID; i += 512) {
        int which = i >> 7, j = i & (HID - 1);
        float v = (which == 0) ? ldx<F32>(b_edge, j)
                : (which == 1) ? ldx<F32>(b_k, j)
                : (which == 2) ? ldx<F32>(b_v, j)
                : (which == 3) ? ldx<F32>(b_o1, j)
                               : ldx<F32>(W_o2, j);
        sm.sBias[i] = v;
    }
    for (int i = t; i < NREL * HID; i += 512)
        sm.sQf[i] = Qtab[i];
    __syncthreads();

    // Per-lane node-row pointers for this lane's A-row (GEMM1 direct loads).
    const void* rowSrc;
    const void* rowTgt;
    if (GBF16) {
        rowSrc = (const void*)((const unsigned short*)gsrc + (size_t)sm.sSrc[aRow] * EMB);
        rowTgt = (const void*)((const unsigned short*)gsrc + (size_t)sm.sTgt[aRow] * EMB);
    } else {
        rowSrc = (const void*)((const float*)gsrc + (size_t)sm.sSrc[aRow] * EMB);
        rowTgt = (const void*)((const float*)gsrc + (size_t)sm.sTgt[aRow] * EMB);
    }

    char* const ldsWaveB0 = (char*)sm.SB[0] + w * 1024;
    char* const ldsWaveB1 = (char*)sm.SB[1] + w * 1024;

    #define LOAD_A(kc, s) \
        loadA8<GBF16>(((kc) < 8) ? rowSrc : rowTgt, ((kc) & 7) * 32 + (s) * 16 + h5 * 8)
    #define STAGE_B(WT, kc, buf)                                                 \
        gload16((WT) + (kc) * 4096 + t * 8, (buf) ? ldsWaveB1 : ldsWaveB0);

    #define MFMA_AR(slot, buf, accv)                                             \
    {                                                                            \
        const char* sb_ = (const char*)sm.SB[(buf)];                             \
        _Pragma("unroll")                                                        \
        for (int s_ = 0; s_ < 2; ++s_) {                                         \
            _Pragma("unroll")                                                    \
            for (int ct_ = 0; ct_ < 2; ++ct_) {                                  \
                bf16x8 b_ = *(const bf16x8*)                                     \
                    (sb_ + ((s_ * 256 + h5 * 128 + 64 * cg2 + 32 * ct_ + c) << 4)); \
                accv[ct_] = __builtin_amdgcn_mfma_f32_32x32x16_bf16(             \
                                aR[slot][s_], b_, accv[ct_], 0, 0, 0);           \
            }                                                                    \
        }                                                                        \
    }

    #define MFMA_H(kc, buf, accv)                                                \
    {                                                                            \
        const char* sb_ = (const char*)sm.SB[(buf)];                             \
        _Pragma("unroll")                                                        \
        for (int s_ = 0; s_ < 2; ++s_) {                                         \
            bf16x8 a_ = *(const bf16x8*)((const char*)sm.sHid +                  \
                         ((((kc) * 4 + s_ * 2 + h5) * SHSTR + aRow) << 4));      \
            _Pragma("unroll")                                                    \
            for (int ct_ = 0; ct_ < 2; ++ct_) {                                  \
                bf16x8 b_ = *(const bf16x8*)                                     \
                    (sb_ + ((s_ * 256 + h5 * 128 + 64 * cg2 + 32 * ct_ + c) << 4)); \
                accv[ct_] = __builtin_amdgcn_mfma_f32_32x32x16_bf16(             \
                                a_, b_, accv[ct_], 0, 0, 0);                     \
            }                                                                    \
        }                                                                        \
    }

    // ---- GEMM1: hid = relu([src|tgt] @ W_edge + b_edge), K=512, 16 chunks ----
    f32x16 acc[2];
    acc[0] = (f32x16)(0.0f); acc[1] = (f32x16)(0.0f);
    {
        bf16x8 aR[4][2];                     // rolling A buffer, depth 4
        #pragma unroll
        for (int p = 0; p < 3; ++p) {        // prologue: A0..A2
            aR[p][0] = LOAD_A(p, 0);
            aR[p][1] = LOAD_A(p, 1);
        }
        STAGE_B(WTe, 0, 0);                  // prologue: B0, B1
        STAGE_B(WTe, 1, 1);
        #pragma unroll
        for (int kc = 0; kc < 16; ++kc) {
            int buf = kc & 1;
            // counted wait: B(kc) landed (see issue-order derivation in notes);
            // compiler adds its own dep-waits for aR reads.
            if (kc == 0)      { WAITVL(1); }
            else if (kc < 14) { WAITVL(3); }
            else if (kc == 14){ WAITVL(1); }
            else              { WAITVL(0); }
            sbar();                          // SB[buf] visible to all waves
            MFMA_AR((kc & 3), buf, acc);
            sbar();                          // SB[buf] consumed by all waves
            if (kc < 13) {                   // A(kc+3) -> slot (kc+3)&3
                aR[(kc + 3) & 3][0] = LOAD_A(kc + 3, 0);
                aR[(kc + 3) & 3][1] = LOAD_A(kc + 3, 1);
            }
            if (kc < 14) STAGE_B(WTe, kc + 2, buf);
        }
    }
    // K-GEMM prefetch (flies across the epilogue + lgkm phase barrier)
    STAGE_B(WTk, 0, 0); STAGE_B(WTk, 1, 1);
    {   // epilogue: + b_edge, relu -> sHid (bf16, padded fragment order)
        #pragma unroll
        for (int ct = 0; ct < 2; ++ct) {
            int col = 64 * cg2 + 32 * ct + c;
            float bb = sm.sBias[col];
            #pragma unroll
            for (int r = 0; r < 16; ++r) {
                int erow = 32 * rt + (r & 3) + 8 * (r >> 2) + 4 * h5;
                sm.sHid[shid_idx(erow, col)] = f32_to_bf16(fmaxf(acc[ct][r] + bb, 0.f));
            }
        }
    }
    bar_lds();                               // sHid visible; K loads in flight

    // ---- K GEMM: K=128, 4 chunks ----
    f32x16 kacc[2];
    kacc[0] = (f32x16)(0.0f); kacc[1] = (f32x16)(0.0f);
    #pragma unroll
    for (int kc = 0; kc < 4; ++kc) {
        int buf = kc & 1;
        if (kc < 3) { WAITVL(1); } else { WAITVL(0); }
        sbar();
        MFMA_H(kc, buf, kacc);
        sbar();
        if (kc < 2) STAGE_B(WTk, kc + 2, buf);
    }
    STAGE_B(WTv, 0, 0); STAGE_B(WTv, 1, 1);  // V prefetch across scores/softmax

    // ---- scores[e][h] = sum_col Q[rel][col]*(K+bk)[e][col] / sqrt(32) ----
    {
        float ps[2][16];
        #pragma unroll
        for (int ct = 0; ct < 2; ++ct) {
            int col = 64 * cg2 + 32 * ct + c;
            float bk = sm.sBias[HID + col];
            #pragma unroll
            for (int r = 0; r < 16; ++r) {
                int erow = 32 * rt + (r & 3) + 8 * (r >> 2) + 4 * h5;
                ps[ct][r] = (kacc[ct][r] + bk) * sm.sQf[sm.sRel[erow] * HID + col];
            }
        }
        #pragma unroll
        for (int m = 1; m < 32; m <<= 1)
            #pragma unroll
            for (int ct = 0; ct < 2; ++ct)
                #pragma unroll
                for (int r = 0; r < 16; ++r)
                    ps[ct][r] += __shfl_xor(ps[ct][r], m, 64);
        if (c == 0) {
            const float inv = 0.17677669529663687f;   // 1/sqrt(32)
            #pragma unroll
            for (int ct = 0; ct < 2; ++ct) {
                int head = 2 * cg2 + ct;
                #pragma unroll
                for (int r = 0; r < 16; ++r) {
                    int erow = 32 * rt + (r & 3) + 8 * (r >> 2) + 4 * h5;
                    sm.sSc[erow][head] = ps[ct][r] * inv;
                }
            }
        }
    }
    bar_lds();
    if (t < TE) {   // softmax over 4 heads
        float s0 = sm.sSc[t][0], s1 = sm.sSc[t][1];
        float s2 = sm.sSc[t][2], s3 = sm.sSc[t][3];
        float m = fmaxf(fmaxf(s0, s1), fmaxf(s2, s3));
        float e0 = expf(s0 - m), e1 = expf(s1 - m);
        float e2 = expf(s2 - m), e3 = expf(s3 - m);
        float den = e0 + e1 + e2 + e3;
        sm.sAttn[t][0] = e0 / den; sm.sAttn[t][1] = e1 / den;
        sm.sAttn[t][2] = e2 / den; sm.sAttn[t][3] = e3 / den;
    }
    bar_lds();

    // ---- V GEMM ----
    f32x16 vacc[2];
    vacc[0] = (f32x16)(0.0f); vacc[1] = (f32x16)(0.0f);
    #pragma unroll
    for (int kc = 0; kc < 4; ++kc) {
        int buf = kc & 1;
        if (kc < 3) { WAITVL(1); } else { WAITVL(0); }
        sbar();
        MFMA_H(kc, buf, vacc);
        sbar();
        if (kc < 2) STAGE_B(WTv, kc + 2, buf);
    }
    STAGE_B(WTo1, 0, 0); STAGE_B(WTo1, 1, 1);  // O prefetch across attend

    // ---- attend + residual (in-place on sHid; element-owner = this lane;
    //      all waves' V-GEMM sHid reads completed at the loop's last sbar) ----
    {
        #pragma unroll
        for (int ct = 0; ct < 2; ++ct) {
            int col  = 64 * cg2 + 32 * ct + c;
            int head = 2 * cg2 + ct;
            float bv = sm.sBias[2 * HID + col];
            #pragma unroll
            for (int r = 0; r < 16; ++r) {
                int erow = 32 * rt + (r & 3) + 8 * (r >> 2) + 4 * h5;
                float at = sm.sAttn[erow][head];
                int   si = shid_idx(erow, col);
                float hv = bf16_to_f32(sm.sHid[si]);
                sm.sHid[si] = f32_to_bf16(at * (vacc[ct][r] + bv) + hv);
            }
        }
    }
    bar_lds();                               // updated sHid visible

    // ---- GEMM3 + final dot with W_o2 ----
    f32x16 oacc[2];
    oacc[0] = (f32x16)(0.0f); oacc[1] = (f32x16)(0.0f);
    #pragma unroll
    for (int kc = 0; kc < 4; ++kc) {
        int buf = kc & 1;
        if (kc < 3) { WAITVL(1); } else { WAITVL(0); }
        sbar();
        MFMA_H(kc, buf, oacc);
        sbar();
        if (kc < 2) STAGE_B(WTo1, kc + 2, buf);
    }
    {
        float pr[16];
        #pragma unroll
        for (int r = 0; r < 16; ++r) pr[r] = 0.f;
        #pragma unroll
        for (int ct = 0; ct < 2; ++ct) {
            int col = 64 * cg2 + 32 * ct + c;
            float bo = sm.sBias[3 * HID + col];
            float wo = sm.sBias[4 * HID + col];
            #pragma unroll
            for (int r = 0; r < 16; ++r)
                pr[r] += fmaxf(oacc[ct][r] + bo, 0.f) * wo;
        }
        #pragma unroll
        for (int m = 1; m < 32; m <<= 1)
            #pragma unroll
            for (int r = 0; r < 16; ++r)
                pr[r] += __shfl_xor(pr[r], m, 64);
        if (c == 0) {
            #pragma unroll
            for (int r = 0; r < 16; ++r) {
                int erow = 32 * rt + (r & 3) + 8 * (r >> 2) + 4 * h5;
                sm.sPart[erow][cg2] = pr[r];
            }
        }
    }
    bar_lds();
    if (t < TE) {
        int ge = bs + t;
        if (ge < E) {
            float val = sm.sPart[t][0] + sm.sPart[t][1] + ldx<F32>(b_o2, 0);
            // F32 path writes fp32 (round-10 lesson: output buffer is fp32).
            if (F32) ((float*)outp)[ge] = val;
            else     ((unsigned short*)outp)[ge] = f32_to_bf16(val);
        }
    }

    #undef LOAD_A
    #undef STAGE_B
    #undef MFMA_AR
    #undef MFMA_H
}

__global__ __launch_bounds__(512, 4) void RelationAttentionMLPHead_10539849744626_kernel(
    const void* nodeEmb, const unsigned short* nodeBf16, int useConv,
    const int* edgeIdx, const int* relType,
    const unsigned short* WTe, const unsigned short* WTk,
    const unsigned short* WTv, const unsigned short* WTo1,
    const void* b_edge, const void* b_k, const void* b_v,
    const void* b_o1, const void* W_o2, const void* b_o2,
    const float* Qtab, void* outp, int E)
{
    __shared__ Smem sm;     // single allocation shared by all instantiations
    if (detect_f32(nodeEmb)) {
        if (useConv)
            fused_body<true, true >(sm, nodeBf16, edgeIdx, relType, WTe, WTk, WTv, WTo1,
                                    b_edge, b_k, b_v, b_o1, W_o2, b_o2, Qtab, outp, E);
        else
            fused_body<true, false>(sm, nodeEmb, edgeIdx, relType, WTe, WTk, WTv, WTo1,
                                    b_edge, b_k, b_v, b_o1, W_o2, b_o2, Qtab, outp, E);
    } else {
        // input already bf16: gather straight from the input table
        fused_body<false, true>(sm, nodeEmb, edgeIdx, relType, WTe, WTk, WTv, WTo1,
                                b_edge, b_k, b_v, b_o1, W_o2, b_o2, Qtab, outp, E);
    }
}

extern "C" void kernel_launch(void* const* d_in, const int* in_sizes, int n_in,
                              void* d_out, int out_size, void* d_ws, size_t ws_size,
                              hipStream_t stream) {
    (void)n_in;

    const void* nodeEmb = d_in[0];
    const int*  edgeIdx = (const int*)d_in[1];
    const int*  relType = (const int*)d_in[2];
    const void* rel_emb = d_in[3];
    const void* W_edge  = d_in[4];
    const void* b_edge  = d_in[5];
    const void* W_q     = d_in[6];
    const void* b_q     = d_in[7];
    const void* W_k     = d_in[8];
    const void* b_k     = d_in[9];
    const void* W_v     = d_in[10];
    const void* b_v     = d_in[11];
    const void* W_o1    = d_in[12];
    const void* b_o1    = d_in[13];
    const void* W_o2    = d_in[14];
    const void* b_o2    = d_in[15];

    int E = out_size;
    if (E <= 0) E = in_sizes ? in_sizes[2] : 0;
    if (E <= 0) E = 500000;

    unsigned long long nodeElems =
        (in_sizes && in_sizes[0] > 0) ? (unsigned long long)in_sizes[0] : 25600000ull;

    // d_ws layout (recomputed every launch; graph-safe)
    char* ws = (char*)d_ws;
    float*          Qtab     = (float*)ws;                      // 5120 B
    unsigned short* WTe      = (unsigned short*)(ws + 8192);    // 131072 B
    unsigned short* WTk      = (unsigned short*)(ws + 139264);  // 32768 B
    unsigned short* WTv      = (unsigned short*)(ws + 172032);  // 32768 B
    unsigned short* WTo1     = (unsigned short*)(ws + 204800);  // 32768 B
    unsigned short* nodeBf16 = (unsigned short*)(ws + 237568);  // nodeElems*2 B

    size_t need = 237568ull + nodeElems * 2ull;
    int useConv = (ws_size >= need) ? 1 : 0;
    int convBlocks = useConv ? (int)((nodeElems + 2047ull) / 2048ull) : 0;

    prep_kernel<<<convBlocks + 449, 256, 0, stream>>>(
        nodeEmb, W_edge, W_k, W_v, W_o1, rel_emb, W_q, b_q,
        WTe, WTk, WTv, WTo1, Qtab, nodeBf16, convBlocks, nodeElems);

    int grid = (E + TE - 1) / TE;
    if (grid < 1) grid = 1;

    RelationAttentionMLPHead_10539849744626_kernel<<<grid, 512, 0, stream>>>(
        nodeEmb, nodeBf16, useConv, edgeIdx, relType, WTe, WTk, WTv, WTo1,
        b_edge, b_k, b_v, b_o1, W_o2, b_o2, Qtab, d_out, E);
}